// Round 12
// baseline (2084.252 us; speedup 1.0000x reference)
//
#include <hip/hip_runtime.h>
#include <cstdint>
#include <cstddef>

typedef unsigned short u16;
typedef unsigned int u32;
typedef __bf16 bf16x8 __attribute__((ext_vector_type(8)));
typedef float f32x4 __attribute__((ext_vector_type(4)));
typedef short short8_t __attribute__((ext_vector_type(8)));

#define NV 50257
#define NVPAD 50304   // 393 * 128
#define NBLK_LM 393
#define ND 1024
#define NT 1024
#define NH 16
#define NL 6
#define NB 2
#define NM 2048       // B*T
#define NF 4096       // 4*D
#define EPSLN 1e-5f

__device__ __forceinline__ u16 f2bf(float f) {
    unsigned u = __float_as_uint(f);
    return (u16)((u + 0x7fffu + ((u >> 16) & 1u)) >> 16);   // RNE
}
__device__ __forceinline__ float bf2f(u16 h) {
    return __uint_as_float(((unsigned)h) << 16);
}
__device__ __forceinline__ u32 pack2bf(float lo, float hi) {
    return (u32)f2bf(lo) | ((u32)f2bf(hi) << 16);
}

__device__ __forceinline__ void gload_lds16(const u16* g, u16* l) {
    __builtin_amdgcn_global_load_lds((const __attribute__((address_space(1))) void*)g,
                                     (__attribute__((address_space(3))) void*)l, 16, 0, 0);
}

__device__ __forceinline__ float wave_reduce_sum(float v) {
#pragma unroll
    for (int off = 32; off >= 1; off >>= 1) v += __shfl_xor(v, off, 64);
    return v;
}

// ---------------- embedding ----------------
__global__ __launch_bounds__(256) void k_embed(const int* __restrict__ idx,
                                               const float* __restrict__ tok,
                                               const float* __restrict__ pos,
                                               float* __restrict__ x) {
    int m = blockIdx.x;
    int t = m & (NT - 1);
    int tokid = idx[m];
    int d = threadIdx.x * 4;
    float4 a = *(const float4*)(tok + (size_t)tokid * ND + d);
    float4 p = *(const float4*)(pos + (size_t)t * ND + d);
    a.x += p.x; a.y += p.y; a.z += p.z; a.w += p.w;
    *(float4*)(x + (size_t)m * ND + d) = a;
}

// ---------------- layernorm ----------------
__global__ __launch_bounds__(256) void k_layernorm(const float* __restrict__ x,
                                                   const float* __restrict__ g,
                                                   const float* __restrict__ b,
                                                   u16* __restrict__ outb) {
    int m = blockIdx.x;
    int d = threadIdx.x * 4;
    const float4 v = *(const float4*)(x + (size_t)m * ND + d);
    float s = v.x + v.y + v.z + v.w;
    float q = v.x * v.x + v.y * v.y + v.z * v.z + v.w * v.w;
    s = wave_reduce_sum(s);
    q = wave_reduce_sum(q);
    __shared__ float ss[4], sq[4];
    int lane = threadIdx.x & 63, w = threadIdx.x >> 6;
    if (lane == 0) { ss[w] = s; sq[w] = q; }
    __syncthreads();
    s = ss[0] + ss[1] + ss[2] + ss[3];
    q = sq[0] + sq[1] + sq[2] + sq[3];
    float mu = s * (1.0f / ND);
    float var = q * (1.0f / ND) - mu * mu;
    float rstd = rsqrtf(var + EPSLN);
    float4 gg = *(const float4*)(g + d);
    float4 bb = *(const float4*)(b + d);
    ushort4 pk;
    pk.x = f2bf((v.x - mu) * rstd * gg.x + bb.x);
    pk.y = f2bf((v.y - mu) * rstd * gg.y + bb.y);
    pk.z = f2bf((v.z - mu) * rstd * gg.z + bb.z);
    pk.w = f2bf((v.w - mu) * rstd * gg.w + bb.w);
    *(ushort4*)(outb + (size_t)m * ND + d) = pk;
}

// ---------------- LM weight transpose + f32->bf16 (N-padded) ----------------
__global__ __launch_bounds__(256) void k_wtrans(const float* __restrict__ W,
                                                u16* __restrict__ Wt,
                                                int K, int N, int Npad, int hs, int ld) {
    __shared__ float t[32][33];
    const int nb = blockIdx.x << 5, kb = blockIdx.y << 5;
    const int tx = threadIdx.x & 31, tq = threadIdx.x >> 5;
    const int n = nb + tx;
    if (n < N) {
        const int head = n / hs, nc = n - head * hs;
        const float* src = W + (size_t)head * K * hs + nc;
#pragma unroll
        for (int i = 0; i < 4; ++i)
            t[(tq << 2) + i][tx] = src[(size_t)(kb + (tq << 2) + i) * ld];
    } else {
#pragma unroll
        for (int i = 0; i < 4; ++i) t[(tq << 2) + i][tx] = 0.f;
    }
    __syncthreads();
#pragma unroll
    for (int i = 0; i < 4; ++i) {
        const int nn = nb + (tq << 2) + i;
        if (nn < Npad) Wt[(size_t)nn * K + kb + tx] = f2bf(t[tx][(tq << 2) + i]);
    }
}

// ---------------- fused per-layer weight transpose (qkv + wp + w1 + w2, one launch) ----
// 1D grid 12288: [0,3072) wq/wk/wv (per-head hs=64), [3072,4096) wp, [4096,8192) w1,
// [8192,12288) w2.
__global__ __launch_bounds__(256) void k_wtrans_all(const float* __restrict__ Wq,
                                                    const float* __restrict__ Wk,
                                                    const float* __restrict__ Wv,
                                                    const float* __restrict__ Wp,
                                                    const float* __restrict__ W1,
                                                    const float* __restrict__ W2,
                                                    u16* __restrict__ Wqkvt,
                                                    u16* __restrict__ Wpt,
                                                    u16* __restrict__ W1t,
                                                    u16* __restrict__ W2t) {
    __shared__ float t[32][33];
    int bid = blockIdx.x;
    const int tx = threadIdx.x & 31, tq = threadIdx.x >> 5;
    if (bid < 3072) {
        const int z = bid >> 10;
        const float* W = (z == 0) ? Wq : (z == 1) ? Wk : Wv;
        u16* dst = Wqkvt + (size_t)z * ND * ND;
        bid &= 1023;
        const int nb = (bid & 31) << 5, kb = (bid >> 5) << 5;
        const int n = nb + tx;
        const int head = n >> 6, nc = n & 63;
        const float* src = W + (size_t)head * ND * 64 + nc;
#pragma unroll
        for (int i = 0; i < 4; ++i)
            t[(tq << 2) + i][tx] = src[(size_t)(kb + (tq << 2) + i) * 64];
        __syncthreads();
#pragma unroll
        for (int i = 0; i < 4; ++i)
            dst[(size_t)(nb + (tq << 2) + i) * ND + kb + tx] = f2bf(t[tx][(tq << 2) + i]);
        return;
    }
    const float* W; u16* Wt; int K, N, nb, kb;
    if (bid < 4096)      { W = Wp; Wt = Wpt; K = ND; N = ND; bid -= 3072;
                           nb = (bid & 31) << 5; kb = (bid >> 5) << 5; }
    else if (bid < 8192) { W = W1; Wt = W1t; K = ND; N = NF; bid -= 4096;
                           nb = (bid & 127) << 5; kb = (bid >> 7) << 5; }
    else                 { W = W2; Wt = W2t; K = NF; N = ND; bid -= 8192;
                           nb = (bid & 31) << 5; kb = (bid >> 5) << 5; }
#pragma unroll
    for (int i = 0; i < 4; ++i)
        t[(tq << 2) + i][tx] = W[(size_t)(kb + (tq << 2) + i) * N + nb + tx];
    __syncthreads();
#pragma unroll
    for (int i = 0; i < 4; ++i)
        Wt[(size_t)(nb + (tq << 2) + i) * K + kb + tx] = f2bf(t[tx][(tq << 2) + i]);
}

// ---------------- V transpose: qkv[B,T,3072] -> vt[B,H,64,T] (bf16) ----------------
__global__ __launch_bounds__(256) void k_vtrans(const u16* __restrict__ qkv,
                                                u16* __restrict__ vt) {
    __shared__ u16 L[64][72];
    const int tt = blockIdx.x, bh = blockIdx.y;
    const int b = bh >> 4, h = bh & 15;
    const int tid = threadIdx.x;
    const int tr = tid >> 2, dc = (tid & 3) << 4;
    const u16* src = qkv + (size_t)(b * NT + tt * 64 + tr) * 3072 + 2048 + h * 64 + dc;
    short8_t v0 = *(const short8_t*)src;
    short8_t v1 = *(const short8_t*)(src + 8);
#pragma unroll
    for (int j = 0; j < 8; ++j) { L[tr][dc + j] = (u16)v0[j]; L[tr][dc + 8 + j] = (u16)v1[j]; }
    __syncthreads();
    const int dr = tid >> 2, tc = (tid & 3) << 4;
    union { u16 us[16]; short8_t v[2]; } tmp;
#pragma unroll
    for (int j = 0; j < 16; ++j) tmp.us[j] = L[tc + j][dr];
    u16* dst = vt + ((size_t)bh * 64 + dr) * NT + tt * 64 + tc;
    *(short8_t*)dst = tmp.v[0];
    *(short8_t*)(dst + 8) = tmp.v[1];
}

// =====================================================================================
// 256x128-tile 2-phase MFMA GEMM, B DIRECT-FROM-GLOBAL (LDS traffic 88->48 KB per
// block-step; LDS 32 KB -> 4 blocks/CU wave-capped). A stays LDS-staged (reuse=2).
// Variants: PART (LM fused softmax partials), KSPLIT, RELU, NBOUND, OUTBF16.
// =====================================================================================
template <bool RELU, bool NBOUND, bool PART, bool KSPLIT, bool OUTBF16>
__global__ __launch_bounds__(512) void k_gemm_big(
    const u16* __restrict__ A, const u16* __restrict__ Bt,
    const float* __restrict__ bias,
    float* __restrict__ Cf, u16* __restrict__ Cb,
    float* __restrict__ pmax_g, float* __restrict__ psum_g,
    int Ksub, int Ktot, int N, int ldc)
{
    __shared__ u16 As[2][256 * 32];
    const int lin = blockIdx.y * (int)gridDim.x + blockIdx.x;
    const int nwg = (int)gridDim.x * (int)gridDim.y;   // % 8 == 0 for all our shapes
    const int cpx = nwg >> 3;
    const int swz = (lin & 7) * cpx + (lin >> 3);
    const int m0 = (swz & 7) * 256;
    const int n0 = (swz >> 3) * 128;
    const int tid = threadIdx.x;
    const int lane = tid & 63, w = tid >> 6;  // 8 waves
    const int wr = w >> 1, wc = w & 1;        // 4 x 2
    const int lr = lane & 15, kg = lane >> 4;

    const int srow = lane >> 2;
    const int scol = (((lane & 3) ^ ((lane >> 3) & 3)) << 3);   // chunk ^ ((row>>1)&3)
    const int koff = KSPLIT ? (int)blockIdx.z * Ksub : 0;
    const u16* gA0 = A + (size_t)(m0 + w * 16 + srow) * Ktot + koff + scol;
    const u16* gA1 = gA0 + (size_t)128 * Ktot;
    // B fragment base: row n0 + wc*64 + ni*16 + lr, k chunk kg*8 (direct from global)
    const u16* gBf = Bt + (size_t)(n0 + wc * 64 + lr) * Ktot + koff + (kg << 3);

    f32x4 acc[4][4] = {};
    const int nt = Ksub >> 5;

    gload_lds16(gA0, &As[0][w * 512]);
    gload_lds16(gA1, &As[0][4096 + w * 512]);
    __syncthreads();

    int cur = 0;
    for (int t = 0; t < nt; ++t) {
        if (t + 1 < nt) {
            const int ko = (t + 1) << 5;
            gload_lds16(gA0 + ko, &As[cur ^ 1][w * 512]);
            gload_lds16(gA1 + ko, &As[cur ^ 1][4096 + w * 512]);
        }
        bf16x8 bfr[4];
        const int tk = t << 5;
#pragma unroll
        for (int ni = 0; ni < 4; ++ni)
            bfr[ni] = *(const bf16x8*)(gBf + (size_t)(ni * 16) * Ktot + tk);
        bf16x8 af[4];
        const int rsw = ((kg ^ ((lr >> 1) & 3)) << 3);
#pragma unroll
        for (int mi = 0; mi < 4; ++mi)
            af[mi] = *(const bf16x8*)&As[cur][(wr * 64 + mi * 16 + lr) * 32 + rsw];
#pragma unroll
        for (int mi = 0; mi < 4; ++mi)
#pragma unroll
            for (int ni = 0; ni < 4; ++ni)
                acc[mi][ni] = __builtin_amdgcn_mfma_f32_16x16x32_bf16(af[mi], bfr[ni], acc[mi][ni], 0, 0, 0);
        __syncthreads();
        cur ^= 1;
    }

    float* Cz = KSPLIT ? (Cf + (size_t)blockIdx.z * NM * ldc) : Cf;
#pragma unroll
    for (int mi = 0; mi < 4; ++mi)
#pragma unroll
        for (int ni = 0; ni < 4; ++ni)
#pragma unroll
            for (int r = 0; r < 4; ++r) {
                const int row = m0 + wr * 64 + mi * 16 + kg * 4 + r;
                const int col = n0 + wc * 64 + ni * 16 + lr;
                if (NBOUND && col >= N) continue;
                float c = acc[mi][ni][r];
                if (bias) c += bias[col];
                if (RELU) c = fmaxf(c, 0.f);
                if (PART) acc[mi][ni][r] = c;   // keep biased value for partials
                if (OUTBF16) Cb[(size_t)row * ldc + col] = f2bf(c);
                else         Cz[(size_t)row * ldc + col] = c;
            }

    if constexpr (PART) {
        // fused softmax partials over this block's 128 cols (coalesced [nblk][NM])
        float* redm = (float*)As;            // [2][256]
        float* reds = redm + 512;            // [2][256]
#pragma unroll
        for (int mi = 0; mi < 4; ++mi)
#pragma unroll
            for (int r = 0; r < 4; ++r) {
                float vmax = -3.0e38f;
#pragma unroll
                for (int ni = 0; ni < 4; ++ni) {
                    const int col = n0 + wc * 64 + ni * 16 + lr;
                    vmax = fmaxf(vmax, (col < N) ? acc[mi][ni][r] : -3.0e38f);
                }
                vmax = fmaxf(vmax, __shfl_xor(vmax, 1));
                vmax = fmaxf(vmax, __shfl_xor(vmax, 2));
                vmax = fmaxf(vmax, __shfl_xor(vmax, 4));
                vmax = fmaxf(vmax, __shfl_xor(vmax, 8));
                if (lr == 0) redm[wc * 256 + wr * 64 + mi * 16 + kg * 4 + r] = vmax;
            }
        __syncthreads();
#pragma unroll
        for (int mi = 0; mi < 4; ++mi)
#pragma unroll
            for (int r = 0; r < 4; ++r) {
                const int rloc = wr * 64 + mi * 16 + kg * 4 + r;
                const float M = fmaxf(redm[rloc], redm[256 + rloc]);
                float s = 0.f;
#pragma unroll
                for (int ni = 0; ni < 4; ++ni) {
                    const int col = n0 + wc * 64 + ni * 16 + lr;
                    if (col < N) s += __expf(acc[mi][ni][r] - M);
                }
                s += __shfl_xor(s, 1);
                s += __shfl_xor(s, 2);
                s += __shfl_xor(s, 4);
                s += __shfl_xor(s, 8);
                if (lr == 0) reds[wc * 256 + rloc] = s;
            }
        __syncthreads();
        if (tid < 256) {
            const float M = fmaxf(redm[tid], redm[256 + tid]);
            const float S = reds[tid] + reds[256 + tid];
            const int nblk = n0 >> 7;
            pmax_g[(size_t)nblk * NM + m0 + tid] = M;
            psum_g[(size_t)nblk * NM + m0 + tid] = S;
        }
    }
}

// ---------------- 128x128 2-phase MFMA GEMM (QKV; unchanged control) ----------------
template <bool RELU, bool NBOUND, bool OUTBF16>
__global__ __launch_bounds__(256) void k_mfma_gemm(
    const u16* __restrict__ A, const u16* __restrict__ Bt,
    const float* __restrict__ bias,
    float* __restrict__ Cf, u16* __restrict__ Cb,
    int K, int N, int ldc)
{
    __shared__ u16 As[2][128 * 32];
    __shared__ u16 Bs[2][128 * 32];
    const int lin = blockIdx.y * 16 + blockIdx.x;
    const int nwg = (int)gridDim.y * 16;
    const int cpx = nwg >> 3;
    const int swz = (lin & 7) * cpx + (lin >> 3);
    const int m0 = (swz & 15) * 128;
    const int n0 = (swz >> 4) * 128;
    const int tid = threadIdx.x;
    const int lane = tid & 63, wv = tid >> 6;
    const int wr = wv >> 1, wc = wv & 1;
    const int lr = lane & 15, kg = lane >> 4;

    const int srow = lane >> 2;
    const int scol = (((lane & 3) ^ ((lane >> 3) & 3)) << 3);
    const u16* gA0 = A + (size_t)(m0 + wv * 16 + srow) * K + scol;
    const u16* gA1 = gA0 + (size_t)64 * K;
    const u16* gB0 = Bt + (size_t)(n0 + wv * 16 + srow) * K + scol;
    const u16* gB1 = gB0 + (size_t)64 * K;

    f32x4 acc[4][4] = {};
    const int nt = K >> 5;

    gload_lds16(gA0, &As[0][wv * 512]);
    gload_lds16(gA1, &As[0][2048 + wv * 512]);
    gload_lds16(gB0, &Bs[0][wv * 512]);
    gload_lds16(gB1, &Bs[0][2048 + wv * 512]);
    __syncthreads();

    int cur = 0;
    for (int t = 0; t < nt; ++t) {
        if (t + 1 < nt) {
            const int ko = (t + 1) << 5;
            gload_lds16(gA0 + ko, &As[cur ^ 1][wv * 512]);
            gload_lds16(gA1 + ko, &As[cur ^ 1][2048 + wv * 512]);
            gload_lds16(gB0 + ko, &Bs[cur ^ 1][wv * 512]);
            gload_lds16(gB1 + ko, &Bs[cur ^ 1][2048 + wv * 512]);
        }
        bf16x8 af[4], bfr[4];
        const int rsw = ((kg ^ ((lr >> 1) & 3)) << 3);
#pragma unroll
        for (int mi = 0; mi < 4; ++mi) {
            const int R = wr * 64 + mi * 16 + lr;
            af[mi] = *(const bf16x8*)&As[cur][R * 32 + rsw];
        }
#pragma unroll
        for (int ni = 0; ni < 4; ++ni) {
            const int R = wc * 64 + ni * 16 + lr;
            bfr[ni] = *(const bf16x8*)&Bs[cur][R * 32 + rsw];
        }
#pragma unroll
        for (int mi = 0; mi < 4; ++mi)
#pragma unroll
            for (int ni = 0; ni < 4; ++ni)
                acc[mi][ni] = __builtin_amdgcn_mfma_f32_16x16x32_bf16(af[mi], bfr[ni], acc[mi][ni], 0, 0, 0);
        __syncthreads();
        cur ^= 1;
    }
#pragma unroll
    for (int mi = 0; mi < 4; ++mi) {
#pragma unroll
        for (int ni = 0; ni < 4; ++ni) {
#pragma unroll
            for (int r = 0; r < 4; ++r) {
                const int row = m0 + wr * 64 + mi * 16 + kg * 4 + r;
                const int col = n0 + wc * 64 + ni * 16 + lr;
                if (NBOUND && col >= N) continue;
                float c = acc[mi][ni][r];
                if (bias) c += bias[col];
                if (RELU) c = fmaxf(c, 0.f);
                if (OUTBF16) Cb[(size_t)row * ldc + col] = f2bf(c);
                else         Cf[(size_t)row * ldc + col] = c;
            }
        }
    }
}

// ---------------- combine: x += p0+p1+p2+p3 + bias (deterministic order) ----------------
__global__ __launch_bounds__(256) void k_combine4(const float* __restrict__ p,
                                                  const float* __restrict__ bias,
                                                  float* __restrict__ x) {
    const int m = blockIdx.x;
    const int d = threadIdx.x * 4;
    const size_t off = (size_t)m * ND + d;
    float4 a  = *(const float4*)(x + off);
    float4 q0 = *(const float4*)(p + off);
    float4 q1 = *(const float4*)(p + (size_t)NM * ND + off);
    float4 q2 = *(const float4*)(p + (size_t)2 * NM * ND + off);
    float4 q3 = *(const float4*)(p + (size_t)3 * NM * ND + off);
    float4 bb = *(const float4*)(bias + d);
    a.x += ((q0.x + q1.x) + (q2.x + q3.x)) + bb.x;
    a.y += ((q0.y + q1.y) + (q2.y + q3.y)) + bb.y;
    a.z += ((q0.z + q1.z) + (q2.z + q3.z)) + bb.z;
    a.w += ((q0.w + q1.w) + (q2.w + q3.w)) + bb.w;
    *(float4*)(x + off) = a;
}

// ---------------- 128x64-tile MFMA GEMM (proj: N=1024 -> 256 blocks) --------
template <bool RELU, bool RESID, bool OUTBF16>
__global__ __launch_bounds__(256) void k_gemm_n64(
    const u16* __restrict__ A, const u16* __restrict__ Bt,
    const float* __restrict__ bias, const float* __restrict__ resid,
    float* __restrict__ Cf, u16* __restrict__ Cb,
    int K, int ldc)
{
    __shared__ u16 As[2][128 * 32];
    __shared__ u16 Bs[2][64 * 32];
    const int lin = blockIdx.y * 16 + blockIdx.x;
    const int nwg = (int)gridDim.y * 16;
    const int cpx = nwg >> 3;
    const int swz = (lin & 7) * cpx + (lin >> 3);
    const int m0 = (swz & 15) * 128;
    const int n0 = (swz >> 4) * 64;
    const int tid = threadIdx.x;
    const int lane = tid & 63, wv = tid >> 6;
    const int lr = lane & 15, kg = lane >> 4;

    const int srow = lane >> 2;
    const int scol = (((lane & 3) ^ ((lane >> 3) & 3)) << 3);
    const u16* gA0 = A + (size_t)(m0 + wv * 32 + srow) * K + scol;
    const u16* gA1 = gA0 + (size_t)16 * K;
    const u16* gB0 = Bt + (size_t)(n0 + wv * 16 + srow) * K + scol;

    f32x4 acc[2][4] = {};
    const int nt = K >> 5;

    gload_lds16(gA0, &As[0][wv * 1024]);
    gload_lds16(gA1, &As[0][wv * 1024 + 512]);
    gload_lds16(gB0, &Bs[0][wv * 512]);
    __syncthreads();

    int cur = 0;
    for (int t = 0; t < nt; ++t) {
        if (t + 1 < nt) {
            const int ko = (t + 1) << 5;
            gload_lds16(gA0 + ko, &As[cur ^ 1][wv * 1024]);
            gload_lds16(gA1 + ko, &As[cur ^ 1][wv * 1024 + 512]);
            gload_lds16(gB0 + ko, &Bs[cur ^ 1][wv * 512]);
        }
        bf16x8 af[2], bfr[4];
        const int rsw = ((kg ^ ((lr >> 1) & 3)) << 3);
#pragma unroll
        for (int mi = 0; mi < 2; ++mi)
            af[mi] = *(const bf16x8*)&As[cur][(wv * 32 + mi * 16 + lr) * 32 + rsw];
#pragma unroll
        for (int ni = 0; ni < 4; ++ni)
            bfr[ni] = *(const bf16x8*)&Bs[cur][(ni * 16 + lr) * 32 + rsw];
#pragma unroll
        for (int mi = 0; mi < 2; ++mi)
#pragma unroll
            for (int ni = 0; ni < 4; ++ni)
                acc[mi][ni] = __builtin_amdgcn_mfma_f32_16x16x32_bf16(af[mi], bfr[ni], acc[mi][ni], 0, 0, 0);
        __syncthreads();
        cur ^= 1;
    }
#pragma unroll
    for (int mi = 0; mi < 2; ++mi) {
#pragma unroll
        for (int ni = 0; ni < 4; ++ni) {
#pragma unroll
            for (int r = 0; r < 4; ++r) {
                const int row = m0 + wv * 32 + mi * 16 + kg * 4 + r;
                const int col = n0 + ni * 16 + lr;
                float c = acc[mi][ni][r];
                if (bias) c += bias[col];
                if (RELU) c = fmaxf(c, 0.f);
                if (RESID) c += resid[(size_t)row * ldc + col];
                if (OUTBF16) Cb[(size_t)row * ldc + col] = f2bf(c);
                else         Cf[(size_t)row * ldc + col] = c;
            }
        }
    }
}

// ---------------- MFMA flash attention (balanced qt pairing) ----------------
__global__ __launch_bounds__(256) void k_attn_mfma(const u16* __restrict__ qkv,
                                                   const u16* __restrict__ vt,
                                                   u16* __restrict__ ob) {
    const int qt = (blockIdx.y < 16) ? (int)blockIdx.x : 15 - (int)blockIdx.x;
    const int bh = blockIdx.y;
    const int b = bh >> 4, h = bh & 15;
    const int tid = threadIdx.x;
    const int lane = tid & 63, w = tid >> 6;
    const int lr = lane & 15, kg = lane >> 4;

    __shared__ u16 Qs[64 * 64];
    __shared__ u16 Ks[2][64 * 64];
    __shared__ u16 Vs[2][64 * 64];

    const int srow8 = lane >> 3;
    const int csw = ((lane & 7) ^ srow8) << 3;

    {
        const int r0 = w * 8 + srow8;
        gload_lds16(qkv + (size_t)(b * NT + qt * 64 + r0) * 3072 + h * 64 + csw, &Qs[w * 512]);
        gload_lds16(qkv + (size_t)(b * NT + qt * 64 + 32 + r0) * 3072 + h * 64 + csw, &Qs[2048 + w * 512]);
    }
#define STAGE_KV(bb, st)                                                                            \
    {                                                                                               \
        const int r0_ = w * 8 + srow8;                                                              \
        gload_lds16(qkv + (size_t)(b * NT + (st) * 64 + r0_) * 3072 + 1024 + h * 64 + csw,          \
                    &Ks[bb][w * 512]);                                                              \
        gload_lds16(qkv + (size_t)(b * NT + (st) * 64 + 32 + r0_) * 3072 + 1024 + h * 64 + csw,     \
                    &Ks[bb][2048 + w * 512]);                                                       \
        gload_lds16(vt + ((size_t)bh * 64 + r0_) * NT + (st) * 64 + csw, &Vs[bb][w * 512]);         \
        gload_lds16(vt + ((size_t)bh * 64 + 32 + r0_) * NT + (st) * 64 + csw,                       \
                    &Vs[bb][2048 + w * 512]);                                                       \
    }
    STAGE_KV(0, 0);
    __syncthreads();

    bf16x8 qf[2];
    {
        const int qrow = w * 16 + lr;
#pragma unroll
        for (int ds_ = 0; ds_ < 2; ++ds_)
            qf[ds_] = *(const bf16x8*)&Qs[qrow * 64 + ((((ds_ << 2) + kg) ^ (lr & 7)) << 3)];
    }

    float mstate = -3.0e38f, lstate = 0.f;
    f32x4 acc_o[4] = {};
    const int qg = qt * 64 + w * 16 + lr;

    int cur = 0;
    for (int st = 0; st <= qt; ++st) {
        if (st < qt) STAGE_KV(cur ^ 1, st + 1);
        const bool diag = (st == qt);
        const int milim = diag ? w : 3;

        f32x4 acc_s[4] = {};
#pragma unroll
        for (int mi = 0; mi < 4; ++mi) {
            if (mi <= milim) {
                const int srw = mi * 16 + lr;
#pragma unroll
                for (int ds_ = 0; ds_ < 2; ++ds_) {
                    bf16x8 kf = *(const bf16x8*)&Ks[cur][srw * 64 + ((((ds_ << 2) + kg) ^ (lr & 7)) << 3)];
                    acc_s[mi] = __builtin_amdgcn_mfma_f32_16x16x32_bf16(kf, qf[ds_], acc_s[mi], 0, 0, 0);
                }
            }
        }
        float tilemax = -3.0e38f;
#pragma unroll
        for (int mi = 0; mi < 4; ++mi)
#pragma unroll
            for (int r = 0; r < 4; ++r) {
                float x_ = acc_s[mi][r] * 0.125f;
                const int sg = st * 64 + mi * 16 + kg * 4 + r;
                if (mi > milim || sg > qg) x_ = -3.0e38f;
                acc_s[mi][r] = x_;
                tilemax = fmaxf(tilemax, x_);
            }
        tilemax = fmaxf(tilemax, __shfl_xor(tilemax, 16));
        tilemax = fmaxf(tilemax, __shfl_xor(tilemax, 32));
        const float mnew = fmaxf(mstate, tilemax);
        const float rfac = __expf(mstate - mnew);
        mstate = mnew;

        float psum = 0.f;
        u32 pk[4][2];
#pragma unroll
        for (int mi = 0; mi < 4; ++mi) {
            float p0 = __expf(acc_s[mi][0] - mnew);
            float p1 = __expf(acc_s[mi][1] - mnew);
            float p2 = __expf(acc_s[mi][2] - mnew);
            float p3 = __expf(acc_s[mi][3] - mnew);
            psum += p0 + p1 + p2 + p3;
            pk[mi][0] = pack2bf(p0, p1);
            pk[mi][1] = pack2bf(p2, p3);
        }
        psum += __shfl_xor(psum, 16);
        psum += __shfl_xor(psum, 32);
        lstate = lstate * rfac + psum;

        float rf[4];
#pragma unroll
        for (int r = 0; r < 4; ++r) rf[r] = __shfl(rfac, kg * 4 + r);
#pragma unroll
        for (int ni = 0; ni < 4; ++ni)
#pragma unroll
            for (int r = 0; r < 4; ++r) acc_o[ni][r] *= rf[r];

        const int src0 = ((kg & 1) << 5) + lr;
        const int src1 = src0 + 16;
#pragma unroll
        for (int ks_ = 0; ks_ < 2; ++ks_) {
            const u32 lo_a = __shfl((int)pk[ks_ * 2][0], src0);
            const u32 lo_b = __shfl((int)pk[ks_ * 2][1], src0);
            const u32 lo_c = __shfl((int)pk[ks_ * 2][0], src1);
            const u32 lo_d = __shfl((int)pk[ks_ * 2][1], src1);
            const u32 hi_a = __shfl((int)pk[ks_ * 2 + 1][0], src0);
            const u32 hi_b = __shfl((int)pk[ks_ * 2 + 1][1], src0);
            const u32 hi_c = __shfl((int)pk[ks_ * 2 + 1][0], src1);
            const u32 hi_d = __shfl((int)pk[ks_ * 2 + 1][1], src1);
            union { u32 u[4]; bf16x8 v; } pa;
            pa.u[0] = (kg & 2) ? hi_a : lo_a;
            pa.u[1] = (kg & 2) ? hi_b : lo_b;
            pa.u[2] = (kg & 2) ? hi_c : lo_c;
            pa.u[3] = (kg & 2) ? hi_d : lo_d;
#pragma unroll
            for (int ni = 0; ni < 4; ++ni) {
                const int drow = ni * 16 + lr;
                bf16x8 vf = *(const bf16x8*)&Vs[cur][drow * 64 + ((((ks_ << 2) + kg) ^ (lr & 7)) << 3)];
                acc_o[ni] = __builtin_amdgcn_mfma_f32_16x16x32_bf16(pa.v, vf, acc_o[ni], 0, 0, 0);
            }
        }
        __syncthreads();
        cur ^= 1;
    }

    float il[4];
#pragma unroll
    for (int r = 0; r < 4; ++r) il[r] = 1.0f / __shfl(lstate, kg * 4 + r);
#pragma unroll
    for (int ni = 0; ni < 4; ++ni)
#pragma unroll
        for (int r = 0; r < 4; ++r) {
            const int q2 = qt * 64 + w * 16 + kg * 4 + r;
            ob[(size_t)(b * NT + q2) * ND + h * 64 + ni * 16 + lr] = f2bf(acc_o[ni][r] * il[r]);
        }
#undef STAGE_KV
}

// ---------------- loss combine from per-block partials ([nblk][NM]) ----------------
__global__ __launch_bounds__(256) void k_losscombine(const float* __restrict__ pmax,
                                                     const float* __restrict__ psum,
                                                     const float* __restrict__ logits,
                                                     const int* __restrict__ targets,
                                                     float* __restrict__ rl) {
    const int row = blockIdx.x * 4 + (threadIdx.x >> 6);
    const int lane = threadIdx.x & 63;
    float M = -3.0e38f;
    for (int j = lane; j < NBLK_LM; j += 64) M = fmaxf(M, pmax[(size_t)j * NM + row]);
#pragma unroll
    for (int off = 32; off >= 1; off >>= 1) M = fmaxf(M, __shfl_xor(M, off, 64));
    float S = 0.f;
    for (int j = lane; j < NBLK_LM; j += 64)
        S += psum[(size_t)j * NM + row] * __expf(pmax[(size_t)j * NM + row] - M);
    S = wave_reduce_sum(S);
    if (lane == 0)
        rl[row] = M + logf(S) - logits[(size_t)row * NV + targets[row]];
}

__global__ __launch_bounds__(256) void k_lossreduce(const float* __restrict__ rl,
                                                    float* __restrict__ out_loss) {
    int tid = threadIdx.x;
    float s = 0.f;
    for (int j = tid; j < NM; j += 256) s += rl[j];
    s = wave_reduce_sum(s);
    __shared__ float sv[4];
    int lane = tid & 63, w = tid >> 6;
    if (lane == 0) sv[w] = s;
    __syncthreads();
    if (tid == 0) out_loss[0] = (sv[0] + sv[1] + sv[2] + sv[3]) * (1.0f / NM);
}

extern "C" void kernel_launch(void* const* d_in, const int* in_sizes, int n_in,
                              void* d_out, int out_size, void* d_ws, size_t ws_size,
                              hipStream_t stream) {
    const int* idx      = (const int*)d_in[0];
    const int* targets  = (const int*)d_in[1];
    const float* tok    = (const float*)d_in[2];
    const float* pos    = (const float*)d_in[3];
    const float* wq     = (const float*)d_in[4];
    const float* wk     = (const float*)d_in[5];
    const float* wv     = (const float*)d_in[6];
    const float* wproj  = (const float*)d_in[7];
    const float* bproj  = (const float*)d_in[8];
    const float* ln1_g  = (const float*)d_in[9];
    const float* ln1_b  = (const float*)d_in[10];
    const float* ln2_g  = (const float*)d_in[11];
    const float* ln2_b  = (const float*)d_in[12];
    const float* w1     = (const float*)d_in[13];
    const float* b1     = (const float*)d_in[14];
    const float* w2     = (const float*)d_in[15];
    const float* b2     = (const float*)d_in[16];
    const float* lnf_g  = (const float*)d_in[17];
    const float* lnf_b  = (const float*)d_in[18];
    const float* lm_w   = (const float*)d_in[19];
    const float* lm_b   = (const float*)d_in[20];
    float* out = (float*)d_out;

    char* wsb = (char*)d_ws;
    auto alloc = [&](size_t bytes) { char* p = wsb; wsb += (bytes + 255) & ~(size_t)255; return p; };
    float* x     = (float*)alloc((size_t)NM * ND * 4);
    u16* h_bf    = (u16*)  alloc((size_t)NM * ND * 2);
    float* rl    = (float*)alloc((size_t)NM * 4);
    float* pmax  = (float*)alloc((size_t)NBLK_LM * NM * 4);
    float* psum  = (float*)alloc((size_t)NBLK_LM * NM * 4);
    char* region = (char*)alloc((size_t)NVPAD * ND * 2);   // 103 MB, aliased
    u16* qkv_bf = (u16*)(region);
    u16* vt_bf  = (u16*)(region + ((size_t)12 << 20));
    u16* ob_bf  = (u16*)(region + ((size_t)16 << 20));
    u16* hid_bf = (u16*)(region + ((size_t)20 << 20));
    u16* wqkv_t = (u16*)(region + ((size_t)36 << 20));
    u16* wp_t   = (u16*)(region + ((size_t)42 << 20));
    u16* w1_t   = (u16*)(region + ((size_t)44 << 20));
    u16* w2_t   = (u16*)(region + ((size_t)52 << 20));
    float* p03  = (float*)(region + ((size_t)60 << 20));   // 4 x 8 MB f32 partials
    u16* lm_t   = (u16*)(region);                          // used only after the layer loop

    k_embed<<<NM, 256, 0, stream>>>(idx, tok, pos, x);

    for (int l = 0; l < NL; ++l) {
        const float* wq_l = wq + (size_t)l * NH * ND * 64;
        const float* wk_l = wk + (size_t)l * NH * ND * 64;
        const float* wv_l = wv + (size_t)l * NH * ND * 64;
        const float* wp_l = wproj + (size_t)l * ND * ND;
        const float* bp_l = bproj + (size_t)l * ND;
        const float* w1_l = w1 + (size_t)l * ND * NF;
        const float* b1_l = b1 + (size_t)l * NF;
        const float* w2_l = w2 + (size_t)l * NF * ND;
        const float* b2_l = b2 + (size_t)l * ND;

        k_layernorm<<<NM, 256, 0, stream>>>(x, ln1_g + (size_t)l * ND, ln1_b + (size_t)l * ND, h_bf);

        k_wtrans_all<<<12288, 256, 0, stream>>>(wq_l, wk_l, wv_l, wp_l, w1_l, w2_l,
                                                wqkv_t, wp_t, w1_t, w2_t);

        k_mfma_gemm<false, false, true><<<dim3(16, 24), 256, 0, stream>>>(
            h_bf, wqkv_t, nullptr, nullptr, qkv_bf, ND, 3 * ND, 3 * ND);

        k_vtrans<<<dim3(NT / 64, NB * NH), 256, 0, stream>>>(qkv_bf, vt_bf);
        k_attn_mfma<<<dim3(NT / 64, NB * NH), 256, 0, stream>>>(qkv_bf, vt_bf, ob_bf);

        k_gemm_n64<false, true, false><<<dim3(16, 16), 256, 0, stream>>>(
            ob_bf, wp_t, bp_l, x, x, nullptr, ND, ND);

        k_layernorm<<<NM, 256, 0, stream>>>(x, ln2_g + (size_t)l * ND, ln2_b + (size_t)l * ND, h_bf);

        // MLP1: 256x128 tile (B direct), grid 8x32 = 256 blocks
        k_gemm_big<true, false, false, false, true><<<dim3(8, 32), 512, 0, stream>>>(
            h_bf, w1_t, b1_l, nullptr, hid_bf, nullptr, nullptr, ND, ND, NF, NF);

        // MLP2: 256x128 tile (B direct), K-split 4 -> grid (8, 8, 4)
        k_gemm_big<false, false, false, true, false><<<dim3(8, 8, 4), 512, 0, stream>>>(
            hid_bf, w2_t, nullptr, p03, nullptr, nullptr, nullptr, NF / 4, NF, ND, ND);
        k_combine4<<<NM, 256, 0, stream>>>(p03, b2_l, x);
    }

    k_layernorm<<<NM, 256, 0, stream>>>(x, lnf_g, lnf_b, h_bf);

    k_wtrans<<<dim3(NVPAD / 32, ND / 32), 256, 0, stream>>>(lm_w, lm_t, ND, NV, NVPAD, NV, NV);
    k_gemm_big<false, true, true, false, false><<<dim3(8, NVPAD / 128), 512, 0, stream>>>(
        h_bf, lm_t, lm_b, out, nullptr, pmax, psum, ND, ND, NV, NV);

    k_losscombine<<<NM / 4, 256, 0, stream>>>(pmax, psum, out, targets, rl);
    k_lossreduce<<<1, 256, 0, stream>>>(rl, out + (size_t)NM * NV);
}

// Round 13
// 1612.103 us; speedup vs baseline: 1.2929x; 1.2929x over previous
//
#include <hip/hip_runtime.h>
#include <cstdint>
#include <cstddef>

typedef unsigned short u16;
typedef unsigned int u32;
typedef __bf16 bf16x8 __attribute__((ext_vector_type(8)));
typedef float f32x4 __attribute__((ext_vector_type(4)));
typedef short short8_t __attribute__((ext_vector_type(8)));

#define NV 50257
#define NVPAD 50304   // 393 * 128
#define NBLK_LM 393
#define ND 1024
#define NT 1024
#define NH 16
#define NL 6
#define NB 2
#define NM 2048       // B*T
#define NF 4096       // 4*D
#define EPSLN 1e-5f

#define VMCNT(n) asm volatile("s_waitcnt vmcnt(" #n ")" ::: "memory")

__device__ __forceinline__ u16 f2bf(float f) {
    unsigned u = __float_as_uint(f);
    return (u16)((u + 0x7fffu + ((u >> 16) & 1u)) >> 16);   // RNE
}
__device__ __forceinline__ float bf2f(u16 h) {
    return __uint_as_float(((unsigned)h) << 16);
}
__device__ __forceinline__ u32 pack2bf(float lo, float hi) {
    return (u32)f2bf(lo) | ((u32)f2bf(hi) << 16);
}

__device__ __forceinline__ void gload_lds16(const u16* g, u16* l) {
    __builtin_amdgcn_global_load_lds((const __attribute__((address_space(1))) void*)g,
                                     (__attribute__((address_space(3))) void*)l, 16, 0, 0);
}

__device__ __forceinline__ float wave_reduce_sum(float v) {
#pragma unroll
    for (int off = 32; off >= 1; off >>= 1) v += __shfl_xor(v, off, 64);
    return v;
}

// ---------------- embedding ----------------
__global__ __launch_bounds__(256) void k_embed(const int* __restrict__ idx,
                                               const float* __restrict__ tok,
                                               const float* __restrict__ pos,
                                               float* __restrict__ x) {
    int m = blockIdx.x;
    int t = m & (NT - 1);
    int tokid = idx[m];
    int d = threadIdx.x * 4;
    float4 a = *(const float4*)(tok + (size_t)tokid * ND + d);
    float4 p = *(const float4*)(pos + (size_t)t * ND + d);
    a.x += p.x; a.y += p.y; a.z += p.z; a.w += p.w;
    *(float4*)(x + (size_t)m * ND + d) = a;
}

// ---------------- layernorm ----------------
__global__ __launch_bounds__(256) void k_layernorm(const float* __restrict__ x,
                                                   const float* __restrict__ g,
                                                   const float* __restrict__ b,
                                                   u16* __restrict__ outb) {
    int m = blockIdx.x;
    int d = threadIdx.x * 4;
    const float4 v = *(const float4*)(x + (size_t)m * ND + d);
    float s = v.x + v.y + v.z + v.w;
    float q = v.x * v.x + v.y * v.y + v.z * v.z + v.w * v.w;
    s = wave_reduce_sum(s);
    q = wave_reduce_sum(q);
    __shared__ float ss[4], sq[4];
    int lane = threadIdx.x & 63, w = threadIdx.x >> 6;
    if (lane == 0) { ss[w] = s; sq[w] = q; }
    __syncthreads();
    s = ss[0] + ss[1] + ss[2] + ss[3];
    q = sq[0] + sq[1] + sq[2] + sq[3];
    float mu = s * (1.0f / ND);
    float var = q * (1.0f / ND) - mu * mu;
    float rstd = rsqrtf(var + EPSLN);
    float4 gg = *(const float4*)(g + d);
    float4 bb = *(const float4*)(b + d);
    ushort4 pk;
    pk.x = f2bf((v.x - mu) * rstd * gg.x + bb.x);
    pk.y = f2bf((v.y - mu) * rstd * gg.y + bb.y);
    pk.z = f2bf((v.z - mu) * rstd * gg.z + bb.z);
    pk.w = f2bf((v.w - mu) * rstd * gg.w + bb.w);
    *(ushort4*)(outb + (size_t)m * ND + d) = pk;
}

// ---------------- LM weight transpose + f32->bf16 (N-padded) ----------------
__global__ __launch_bounds__(256) void k_wtrans(const float* __restrict__ W,
                                                u16* __restrict__ Wt,
                                                int K, int N, int Npad, int hs, int ld) {
    __shared__ float t[32][33];
    const int nb = blockIdx.x << 5, kb = blockIdx.y << 5;
    const int tx = threadIdx.x & 31, tq = threadIdx.x >> 5;
    const int n = nb + tx;
    if (n < N) {
        const int head = n / hs, nc = n - head * hs;
        const float* src = W + (size_t)head * K * hs + nc;
#pragma unroll
        for (int i = 0; i < 4; ++i)
            t[(tq << 2) + i][tx] = src[(size_t)(kb + (tq << 2) + i) * ld];
    } else {
#pragma unroll
        for (int i = 0; i < 4; ++i) t[(tq << 2) + i][tx] = 0.f;
    }
    __syncthreads();
#pragma unroll
    for (int i = 0; i < 4; ++i) {
        const int nn = nb + (tq << 2) + i;
        if (nn < Npad) Wt[(size_t)nn * K + kb + tx] = f2bf(t[tx][(tq << 2) + i]);
    }
}

// ---------------- fused per-layer weight transpose (qkv + wp + w1 + w2) ----------------
__global__ __launch_bounds__(256) void k_wtrans_all(const float* __restrict__ Wq,
                                                    const float* __restrict__ Wk,
                                                    const float* __restrict__ Wv,
                                                    const float* __restrict__ Wp,
                                                    const float* __restrict__ W1,
                                                    const float* __restrict__ W2,
                                                    u16* __restrict__ Wqkvt,
                                                    u16* __restrict__ Wpt,
                                                    u16* __restrict__ W1t,
                                                    u16* __restrict__ W2t) {
    __shared__ float t[32][33];
    int bid = blockIdx.x;
    const int tx = threadIdx.x & 31, tq = threadIdx.x >> 5;
    if (bid < 3072) {
        const int z = bid >> 10;
        const float* W = (z == 0) ? Wq : (z == 1) ? Wk : Wv;
        u16* dst = Wqkvt + (size_t)z * ND * ND;
        bid &= 1023;
        const int nb = (bid & 31) << 5, kb = (bid >> 5) << 5;
        const int n = nb + tx;
        const int head = n >> 6, nc = n & 63;
        const float* src = W + (size_t)head * ND * 64 + nc;
#pragma unroll
        for (int i = 0; i < 4; ++i)
            t[(tq << 2) + i][tx] = src[(size_t)(kb + (tq << 2) + i) * 64];
        __syncthreads();
#pragma unroll
        for (int i = 0; i < 4; ++i)
            dst[(size_t)(nb + (tq << 2) + i) * ND + kb + tx] = f2bf(t[tx][(tq << 2) + i]);
        return;
    }
    const float* W; u16* Wt; int K, N, nb, kb;
    if (bid < 4096)      { W = Wp; Wt = Wpt; K = ND; N = ND; bid -= 3072;
                           nb = (bid & 31) << 5; kb = (bid >> 5) << 5; }
    else if (bid < 8192) { W = W1; Wt = W1t; K = ND; N = NF; bid -= 4096;
                           nb = (bid & 127) << 5; kb = (bid >> 7) << 5; }
    else                 { W = W2; Wt = W2t; K = NF; N = ND; bid -= 8192;
                           nb = (bid & 31) << 5; kb = (bid >> 5) << 5; }
#pragma unroll
    for (int i = 0; i < 4; ++i)
        t[(tq << 2) + i][tx] = W[(size_t)(kb + (tq << 2) + i) * N + nb + tx];
    __syncthreads();
#pragma unroll
    for (int i = 0; i < 4; ++i)
        Wt[(size_t)(nb + (tq << 2) + i) * K + kb + tx] = f2bf(t[tx][(tq << 2) + i]);
}

// ---------------- V transpose: qkv[B,T,3072] -> vt[B,H,64,T] (bf16) ----------------
__global__ __launch_bounds__(256) void k_vtrans(const u16* __restrict__ qkv,
                                                u16* __restrict__ vt) {
    __shared__ u16 L[64][72];
    const int tt = blockIdx.x, bh = blockIdx.y;
    const int b = bh >> 4, h = bh & 15;
    const int tid = threadIdx.x;
    const int tr = tid >> 2, dc = (tid & 3) << 4;
    const u16* src = qkv + (size_t)(b * NT + tt * 64 + tr) * 3072 + 2048 + h * 64 + dc;
    short8_t v0 = *(const short8_t*)src;
    short8_t v1 = *(const short8_t*)(src + 8);
#pragma unroll
    for (int j = 0; j < 8; ++j) { L[tr][dc + j] = (u16)v0[j]; L[tr][dc + 8 + j] = (u16)v1[j]; }
    __syncthreads();
    const int dr = tid >> 2, tc = (tid & 3) << 4;
    union { u16 us[16]; short8_t v[2]; } tmp;
#pragma unroll
    for (int j = 0; j < 16; ++j) tmp.us[j] = L[tc + j][dr];
    u16* dst = vt + ((size_t)bh * 64 + dr) * NT + tt * 64 + tc;
    *(short8_t*)dst = tmp.v[0];
    *(short8_t*)(dst + 8) = tmp.v[1];
}

// =====================================================================================
// 256x128-tile 2-phase MFMA GEMM (R11 proven form: A AND B via LDS). Variants:
// PART (LM fused softmax partials, coalesced [nblk][NM]), KSPLIT, RELU, NBOUND, OUTBF16.
// =====================================================================================
template <bool RELU, bool NBOUND, bool PART, bool KSPLIT, bool OUTBF16>
__global__ __launch_bounds__(512) void k_gemm_big(
    const u16* __restrict__ A, const u16* __restrict__ Bt,
    const float* __restrict__ bias,
    float* __restrict__ Cf, u16* __restrict__ Cb,
    float* __restrict__ pmax_g, float* __restrict__ psum_g,
    int Ksub, int Ktot, int N, int ldc)
{
    __shared__ u16 As[2][256 * 32];
    __shared__ u16 Bs[2][128 * 32];
    const int lin = blockIdx.y * (int)gridDim.x + blockIdx.x;
    const int nwg = (int)gridDim.x * (int)gridDim.y;   // % 8 == 0 for all our shapes
    const int cpx = nwg >> 3;
    const int swz = (lin & 7) * cpx + (lin >> 3);
    const int m0 = (swz & 7) * 256;
    const int n0 = (swz >> 3) * 128;
    const int tid = threadIdx.x;
    const int lane = tid & 63, w = tid >> 6;  // 8 waves
    const int wr = w >> 1, wc = w & 1;        // 4 x 2
    const int lr = lane & 15, kg = lane >> 4;

    const int srow = lane >> 2;
    const int scol = (((lane & 3) ^ ((lane >> 3) & 3)) << 3);   // chunk ^ ((row>>1)&3)
    const int koff = KSPLIT ? (int)blockIdx.z * Ksub : 0;
    const u16* gA0 = A + (size_t)(m0 + w * 16 + srow) * Ktot + koff + scol;
    const u16* gA1 = gA0 + (size_t)128 * Ktot;
    const u16* gB0 = Bt + (size_t)(n0 + w * 16 + srow) * Ktot + koff + scol;

    f32x4 acc[4][4] = {};
    const int nt = Ksub >> 5;

    gload_lds16(gA0, &As[0][w * 512]);
    gload_lds16(gA1, &As[0][4096 + w * 512]);
    gload_lds16(gB0, &Bs[0][w * 512]);
    __syncthreads();

    int cur = 0;
    for (int t = 0; t < nt; ++t) {
        if (t + 1 < nt) {
            const int ko = (t + 1) << 5;
            gload_lds16(gA0 + ko, &As[cur ^ 1][w * 512]);
            gload_lds16(gA1 + ko, &As[cur ^ 1][4096 + w * 512]);
            gload_lds16(gB0 + ko, &Bs[cur ^ 1][w * 512]);
        }
        bf16x8 af[4], bfr[4];
        const int rsw = ((kg ^ ((lr >> 1) & 3)) << 3);
#pragma unroll
        for (int mi = 0; mi < 4; ++mi)
            af[mi] = *(const bf16x8*)&As[cur][(wr * 64 + mi * 16 + lr) * 32 + rsw];
#pragma unroll
        for (int ni = 0; ni < 4; ++ni)
            bfr[ni] = *(const bf16x8*)&Bs[cur][(wc * 64 + ni * 16 + lr) * 32 + rsw];
#pragma unroll
        for (int mi = 0; mi < 4; ++mi)
#pragma unroll
            for (int ni = 0; ni < 4; ++ni)
                acc[mi][ni] = __builtin_amdgcn_mfma_f32_16x16x32_bf16(af[mi], bfr[ni], acc[mi][ni], 0, 0, 0);
        __syncthreads();
        cur ^= 1;
    }

    float* Cz = KSPLIT ? (Cf + (size_t)blockIdx.z * NM * ldc) : Cf;
#pragma unroll
    for (int mi = 0; mi < 4; ++mi)
#pragma unroll
        for (int ni = 0; ni < 4; ++ni)
#pragma unroll
            for (int r = 0; r < 4; ++r) {
                const int row = m0 + wr * 64 + mi * 16 + kg * 4 + r;
                const int col = n0 + wc * 64 + ni * 16 + lr;
                if (NBOUND && col >= N) continue;
                float c = acc[mi][ni][r];
                if (bias) c += bias[col];
                if (RELU) c = fmaxf(c, 0.f);
                if (PART) acc[mi][ni][r] = c;   // keep biased value for partials
                if (OUTBF16) Cb[(size_t)row * ldc + col] = f2bf(c);
                else         Cz[(size_t)row * ldc + col] = c;
            }

    if constexpr (PART) {
        float* redm = (float*)As;            // [2][256]
        float* reds = redm + 512;            // [2][256]
#pragma unroll
        for (int mi = 0; mi < 4; ++mi)
#pragma unroll
            for (int r = 0; r < 4; ++r) {
                float vmax = -3.0e38f;
#pragma unroll
                for (int ni = 0; ni < 4; ++ni) {
                    const int col = n0 + wc * 64 + ni * 16 + lr;
                    vmax = fmaxf(vmax, (col < N) ? acc[mi][ni][r] : -3.0e38f);
                }
                vmax = fmaxf(vmax, __shfl_xor(vmax, 1));
                vmax = fmaxf(vmax, __shfl_xor(vmax, 2));
                vmax = fmaxf(vmax, __shfl_xor(vmax, 4));
                vmax = fmaxf(vmax, __shfl_xor(vmax, 8));
                if (lr == 0) redm[wc * 256 + wr * 64 + mi * 16 + kg * 4 + r] = vmax;
            }
        __syncthreads();
#pragma unroll
        for (int mi = 0; mi < 4; ++mi)
#pragma unroll
            for (int r = 0; r < 4; ++r) {
                const int rloc = wr * 64 + mi * 16 + kg * 4 + r;
                const float M = fmaxf(redm[rloc], redm[256 + rloc]);
                float s = 0.f;
#pragma unroll
                for (int ni = 0; ni < 4; ++ni) {
                    const int col = n0 + wc * 64 + ni * 16 + lr;
                    if (col < N) s += __expf(acc[mi][ni][r] - M);
                }
                s += __shfl_xor(s, 1);
                s += __shfl_xor(s, 2);
                s += __shfl_xor(s, 4);
                s += __shfl_xor(s, 8);
                if (lr == 0) reds[wc * 256 + rloc] = s;
            }
        __syncthreads();
        if (tid < 256) {
            const float M = fmaxf(redm[tid], redm[256 + tid]);
            const float S = reds[tid] + reds[256 + tid];
            const int nblk = n0 >> 7;
            pmax_g[(size_t)nblk * NM + m0 + tid] = M;
            psum_g[(size_t)nblk * NM + m0 + tid] = S;
        }
    }
}

// ---------------- 128x128 2-phase MFMA GEMM (QKV) ----------------
template <bool RELU, bool NBOUND, bool OUTBF16>
__global__ __launch_bounds__(256) void k_mfma_gemm(
    const u16* __restrict__ A, const u16* __restrict__ Bt,
    const float* __restrict__ bias,
    float* __restrict__ Cf, u16* __restrict__ Cb,
    int K, int N, int ldc)
{
    __shared__ u16 As[2][128 * 32];
    __shared__ u16 Bs[2][128 * 32];
    const int lin = blockIdx.y * 16 + blockIdx.x;
    const int nwg = (int)gridDim.y * 16;
    const int cpx = nwg >> 3;
    const int swz = (lin & 7) * cpx + (lin >> 3);
    const int m0 = (swz & 15) * 128;
    const int n0 = (swz >> 4) * 128;
    const int tid = threadIdx.x;
    const int lane = tid & 63, wv = tid >> 6;
    const int wr = wv >> 1, wc = wv & 1;
    const int lr = lane & 15, kg = lane >> 4;

    const int srow = lane >> 2;
    const int scol = (((lane & 3) ^ ((lane >> 3) & 3)) << 3);
    const u16* gA0 = A + (size_t)(m0 + wv * 16 + srow) * K + scol;
    const u16* gA1 = gA0 + (size_t)64 * K;
    const u16* gB0 = Bt + (size_t)(n0 + wv * 16 + srow) * K + scol;
    const u16* gB1 = gB0 + (size_t)64 * K;

    f32x4 acc[4][4] = {};
    const int nt = K >> 5;

    gload_lds16(gA0, &As[0][wv * 512]);
    gload_lds16(gA1, &As[0][2048 + wv * 512]);
    gload_lds16(gB0, &Bs[0][wv * 512]);
    gload_lds16(gB1, &Bs[0][2048 + wv * 512]);
    __syncthreads();

    int cur = 0;
    for (int t = 0; t < nt; ++t) {
        if (t + 1 < nt) {
            const int ko = (t + 1) << 5;
            gload_lds16(gA0 + ko, &As[cur ^ 1][wv * 512]);
            gload_lds16(gA1 + ko, &As[cur ^ 1][2048 + wv * 512]);
            gload_lds16(gB0 + ko, &Bs[cur ^ 1][wv * 512]);
            gload_lds16(gB1 + ko, &Bs[cur ^ 1][2048 + wv * 512]);
        }
        bf16x8 af[4], bfr[4];
        const int rsw = ((kg ^ ((lr >> 1) & 3)) << 3);
#pragma unroll
        for (int mi = 0; mi < 4; ++mi) {
            const int R = wr * 64 + mi * 16 + lr;
            af[mi] = *(const bf16x8*)&As[cur][R * 32 + rsw];
        }
#pragma unroll
        for (int ni = 0; ni < 4; ++ni) {
            const int R = wc * 64 + ni * 16 + lr;
            bfr[ni] = *(const bf16x8*)&Bs[cur][R * 32 + rsw];
        }
#pragma unroll
        for (int mi = 0; mi < 4; ++mi)
#pragma unroll
            for (int ni = 0; ni < 4; ++ni)
                acc[mi][ni] = __builtin_amdgcn_mfma_f32_16x16x32_bf16(af[mi], bfr[ni], acc[mi][ni], 0, 0, 0);
        __syncthreads();
        cur ^= 1;
    }
#pragma unroll
    for (int mi = 0; mi < 4; ++mi) {
#pragma unroll
        for (int ni = 0; ni < 4; ++ni) {
#pragma unroll
            for (int r = 0; r < 4; ++r) {
                const int row = m0 + wr * 64 + mi * 16 + kg * 4 + r;
                const int col = n0 + wc * 64 + ni * 16 + lr;
                if (NBOUND && col >= N) continue;
                float c = acc[mi][ni][r];
                if (bias) c += bias[col];
                if (RELU) c = fmaxf(c, 0.f);
                if (OUTBF16) Cb[(size_t)row * ldc + col] = f2bf(c);
                else         Cf[(size_t)row * ldc + col] = c;
            }
        }
    }
}

// ---------------- combine: x += p0+p1+p2+p3 + bias ----------------
__global__ __launch_bounds__(256) void k_combine4(const float* __restrict__ p,
                                                  const float* __restrict__ bias,
                                                  float* __restrict__ x) {
    const int m = blockIdx.x;
    const int d = threadIdx.x * 4;
    const size_t off = (size_t)m * ND + d;
    float4 a  = *(const float4*)(x + off);
    float4 q0 = *(const float4*)(p + off);
    float4 q1 = *(const float4*)(p + (size_t)NM * ND + off);
    float4 q2 = *(const float4*)(p + (size_t)2 * NM * ND + off);
    float4 q3 = *(const float4*)(p + (size_t)3 * NM * ND + off);
    float4 bb = *(const float4*)(bias + d);
    a.x += ((q0.x + q1.x) + (q2.x + q3.x)) + bb.x;
    a.y += ((q0.y + q1.y) + (q2.y + q3.y)) + bb.y;
    a.z += ((q0.z + q1.z) + (q2.z + q3.z)) + bb.z;
    a.w += ((q0.w + q1.w) + (q2.w + q3.w)) + bb.w;
    *(float4*)(x + off) = a;
}

// ---------------- 128x64-tile MFMA GEMM (proj) --------
template <bool RELU, bool RESID, bool OUTBF16>
__global__ __launch_bounds__(256) void k_gemm_n64(
    const u16* __restrict__ A, const u16* __restrict__ Bt,
    const float* __restrict__ bias, const float* __restrict__ resid,
    float* __restrict__ Cf, u16* __restrict__ Cb,
    int K, int ldc)
{
    __shared__ u16 As[2][128 * 32];
    __shared__ u16 Bs[2][64 * 32];
    const int lin = blockIdx.y * 16 + blockIdx.x;
    const int nwg = (int)gridDim.y * 16;
    const int cpx = nwg >> 3;
    const int swz = (lin & 7) * cpx + (lin >> 3);
    const int m0 = (swz & 15) * 128;
    const int n0 = (swz >> 4) * 64;
    const int tid = threadIdx.x;
    const int lane = tid & 63, wv = tid >> 6;
    const int lr = lane & 15, kg = lane >> 4;

    const int srow = lane >> 2;
    const int scol = (((lane & 3) ^ ((lane >> 3) & 3)) << 3);
    const u16* gA0 = A + (size_t)(m0 + wv * 32 + srow) * K + scol;
    const u16* gA1 = gA0 + (size_t)16 * K;
    const u16* gB0 = Bt + (size_t)(n0 + wv * 16 + srow) * K + scol;

    f32x4 acc[2][4] = {};
    const int nt = K >> 5;

    gload_lds16(gA0, &As[0][wv * 1024]);
    gload_lds16(gA1, &As[0][wv * 1024 + 512]);
    gload_lds16(gB0, &Bs[0][wv * 512]);
    __syncthreads();

    int cur = 0;
    for (int t = 0; t < nt; ++t) {
        if (t + 1 < nt) {
            const int ko = (t + 1) << 5;
            gload_lds16(gA0 + ko, &As[cur ^ 1][wv * 1024]);
            gload_lds16(gA1 + ko, &As[cur ^ 1][wv * 1024 + 512]);
            gload_lds16(gB0 + ko, &Bs[cur ^ 1][wv * 512]);
        }
        bf16x8 af[2], bfr[4];
        const int rsw = ((kg ^ ((lr >> 1) & 3)) << 3);
#pragma unroll
        for (int mi = 0; mi < 2; ++mi)
            af[mi] = *(const bf16x8*)&As[cur][(wv * 32 + mi * 16 + lr) * 32 + rsw];
#pragma unroll
        for (int ni = 0; ni < 4; ++ni)
            bfr[ni] = *(const bf16x8*)&Bs[cur][(ni * 16 + lr) * 32 + rsw];
#pragma unroll
        for (int mi = 0; mi < 2; ++mi)
#pragma unroll
            for (int ni = 0; ni < 4; ++ni)
                acc[mi][ni] = __builtin_amdgcn_mfma_f32_16x16x32_bf16(af[mi], bfr[ni], acc[mi][ni], 0, 0, 0);
        __syncthreads();
        cur ^= 1;
    }
#pragma unroll
    for (int mi = 0; mi < 2; ++mi) {
#pragma unroll
        for (int ni = 0; ni < 4; ++ni) {
#pragma unroll
            for (int r = 0; r < 4; ++r) {
                const int row = m0 + wv * 32 + mi * 16 + kg * 4 + r;
                const int col = n0 + ni * 16 + lr;
                float c = acc[mi][ni][r];
                if (bias) c += bias[col];
                if (RELU) c = fmaxf(c, 0.f);
                if (RESID) c += resid[(size_t)row * ldc + col];
                if (OUTBF16) Cb[(size_t)row * ldc + col] = f2bf(c);
                else         Cf[(size_t)row * ldc + col] = c;
            }
        }
    }
}

// ---------------- MFMA flash attention: 3-buffer KV pipeline, counted vmcnt ----------
// (R7 correctness-proven loop + R10 balanced-qt pairing.)
__global__ __launch_bounds__(256) void k_attn_mfma(const u16* __restrict__ qkv,
                                                   const u16* __restrict__ vt,
                                                   u16* __restrict__ ob) {
    const int qt = (blockIdx.y < 16) ? (int)blockIdx.x : 15 - (int)blockIdx.x;
    const int bh = blockIdx.y;
    const int b = bh >> 4, h = bh & 15;
    const int tid = threadIdx.x;
    const int lane = tid & 63, w = tid >> 6;
    const int lr = lane & 15, kg = lane >> 4;

    __shared__ u16 Qs[64 * 64];
    __shared__ u16 Ks[3][64 * 64];
    __shared__ u16 Vs[3][64 * 64];

    const int srow8 = lane >> 3;
    const int csw = ((lane & 7) ^ srow8) << 3;

    {   // stage Q (2 loads, oldest)
        const int r0 = w * 8 + srow8;
        gload_lds16(qkv + (size_t)(b * NT + qt * 64 + r0) * 3072 + h * 64 + csw, &Qs[w * 512]);
        gload_lds16(qkv + (size_t)(b * NT + qt * 64 + 32 + r0) * 3072 + h * 64 + csw, &Qs[2048 + w * 512]);
    }
#define STAGE_KV(bb, st)                                                                            \
    {                                                                                               \
        const int r0_ = w * 8 + srow8;                                                              \
        gload_lds16(qkv + (size_t)(b * NT + (st) * 64 + r0_) * 3072 + 1024 + h * 64 + csw,          \
                    &Ks[bb][w * 512]);                                                              \
        gload_lds16(qkv + (size_t)(b * NT + (st) * 64 + 32 + r0_) * 3072 + 1024 + h * 64 + csw,     \
                    &Ks[bb][2048 + w * 512]);                                                       \
        gload_lds16(vt + ((size_t)bh * 64 + r0_) * NT + (st) * 64 + csw, &Vs[bb][w * 512]);         \
        gload_lds16(vt + ((size_t)bh * 64 + 32 + r0_) * NT + (st) * 64 + csw,                       \
                    &Vs[bb][2048 + w * 512]);                                                       \
    }
    STAGE_KV(0, 0);
    if (qt >= 1) STAGE_KV(1, 1);
    if (qt == 0) { VMCNT(0); } else { VMCNT(4); }   // Q + KV0 complete; KV1 in flight
    __builtin_amdgcn_s_barrier();

    bf16x8 qf[2];
    {
        const int qrow = w * 16 + lr;
#pragma unroll
        for (int ds_ = 0; ds_ < 2; ++ds_)
            qf[ds_] = *(const bf16x8*)&Qs[qrow * 64 + ((((ds_ << 2) + kg) ^ (lr & 7)) << 3)];
    }

    float mstate = -3.0e38f, lstate = 0.f;
    f32x4 acc_o[4] = {};
    const int qg = qt * 64 + w * 16 + lr;

    int cur = 0;
    for (int st = 0; st <= qt; ++st) {
        if (st > 0) {
            if (st < qt) { VMCNT(4); } else { VMCNT(0); }
            __builtin_amdgcn_s_barrier();
        }
        if (st + 2 <= qt) {
            int tgt = cur + 2; if (tgt >= 3) tgt -= 3;
            STAGE_KV(tgt, st + 2);
        }
        const bool diag = (st == qt);
        const int milim = diag ? w : 3;

        f32x4 acc_s[4] = {};
#pragma unroll
        for (int mi = 0; mi < 4; ++mi) {
            if (mi <= milim) {
                const int srw = mi * 16 + lr;
#pragma unroll
                for (int ds_ = 0; ds_ < 2; ++ds_) {
                    bf16x8 kf = *(const bf16x8*)&Ks[cur][srw * 64 + ((((ds_ << 2) + kg) ^ (lr & 7)) << 3)];
                    acc_s[mi] = __builtin_amdgcn_mfma_f32_16x16x32_bf16(kf, qf[ds_], acc_s[mi], 0, 0, 0);
                }
            }
        }
        float tilemax = -3.0e38f;
#pragma unroll
        for (int mi = 0; mi < 4; ++mi)
#pragma unroll
            for (int r = 0; r < 4; ++r) {
                float x_ = acc_s[mi][r] * 0.125f;
                const int sg = st * 64 + mi * 16 + kg * 4 + r;
                if (mi > milim || sg > qg) x_ = -3.0e38f;
                acc_s[mi][r] = x_;
                tilemax = fmaxf(tilemax, x_);
            }
        tilemax = fmaxf(tilemax, __shfl_xor(tilemax, 16));
        tilemax = fmaxf(tilemax, __shfl_xor(tilemax, 32));
        const float mnew = fmaxf(mstate, tilemax);
        const float rfac = __expf(mstate - mnew);
        mstate = mnew;

        float psum = 0.f;
        u32 pk[4][2];
#pragma unroll
        for (int mi = 0; mi < 4; ++mi) {
            float p0 = __expf(acc_s[mi][0] - mnew);
            float p1 = __expf(acc_s[mi][1] - mnew);
            float p2 = __expf(acc_s[mi][2] - mnew);
            float p3 = __expf(acc_s[mi][3] - mnew);
            psum += p0 + p1 + p2 + p3;
            pk[mi][0] = pack2bf(p0, p1);
            pk[mi][1] = pack2bf(p2, p3);
        }
        psum += __shfl_xor(psum, 16);
        psum += __shfl_xor(psum, 32);
        lstate = lstate * rfac + psum;

        float rf[4];
#pragma unroll
        for (int r = 0; r < 4; ++r) rf[r] = __shfl(rfac, kg * 4 + r);
#pragma unroll
        for (int ni = 0; ni < 4; ++ni)
#pragma unroll
            for (int r = 0; r < 4; ++r) acc_o[ni][r] *= rf[r];

        const int src0 = ((kg & 1) << 5) + lr;
        const int src1 = src0 + 16;
#pragma unroll
        for (int ks_ = 0; ks_ < 2; ++ks_) {
            const u32 lo_a = __shfl((int)pk[ks_ * 2][0], src0);
            const u32 lo_b = __shfl((int)pk[ks_ * 2][1], src0);
            const u32 lo_c = __shfl((int)pk[ks_ * 2][0], src1);
            const u32 lo_d = __shfl((int)pk[ks_ * 2][1], src1);
            const u32 hi_a = __shfl((int)pk[ks_ * 2 + 1][0], src0);
            const u32 hi_b = __shfl((int)pk[ks_ * 2 + 1][1], src0);
            const u32 hi_c = __shfl((int)pk[ks_ * 2 + 1][0], src1);
            const u32 hi_d = __shfl((int)pk[ks_ * 2 + 1][1], src1);
            union { u32 u[4]; bf16x8 v; } pa;
            pa.u[0] = (kg & 2) ? hi_a : lo_a;
            pa.u[1] = (kg & 2) ? hi_b : lo_b;
            pa.u[2] = (kg & 2) ? hi_c : lo_c;
            pa.u[3] = (kg & 2) ? hi_d : lo_d;
#pragma unroll
            for (int ni = 0; ni < 4; ++ni) {
                const int drow = ni * 16 + lr;
                bf16x8 vf = *(const bf16x8*)&Vs[cur][drow * 64 + ((((ks_ << 2) + kg) ^ (lr & 7)) << 3)];
                acc_o[ni] = __builtin_amdgcn_mfma_f32_16x16x32_bf16(pa.v, vf, acc_o[ni], 0, 0, 0);
            }
        }
        cur = (cur == 2) ? 0 : cur + 1;
    }

    float il[4];
#pragma unroll
    for (int r = 0; r < 4; ++r) il[r] = 1.0f / __shfl(lstate, kg * 4 + r);
#pragma unroll
    for (int ni = 0; ni < 4; ++ni)
#pragma unroll
        for (int r = 0; r < 4; ++r) {
            const int q2 = qt * 64 + w * 16 + kg * 4 + r;
            ob[(size_t)(b * NT + q2) * ND + h * 64 + ni * 16 + lr] = f2bf(acc_o[ni][r] * il[r]);
        }
#undef STAGE_KV
}

// ---------------- loss combine from per-block partials ([nblk][NM]) ----------------
__global__ __launch_bounds__(256) void k_losscombine(const float* __restrict__ pmax,
                                                     const float* __restrict__ psum,
                                                     const float* __restrict__ logits,
                                                     const int* __restrict__ targets,
                                                     float* __restrict__ rl) {
    const int row = blockIdx.x * 4 + (threadIdx.x >> 6);
    const int lane = threadIdx.x & 63;
    float M = -3.0e38f;
    for (int j = lane; j < NBLK_LM; j += 64) M = fmaxf(M, pmax[(size_t)j * NM + row]);
#pragma unroll
    for (int off = 32; off >= 1; off >>= 1) M = fmaxf(M, __shfl_xor(M, off, 64));
    float S = 0.f;
    for (int j = lane; j < NBLK_LM; j += 64)
        S += psum[(size_t)j * NM + row] * __expf(pmax[(size_t)j * NM + row] - M);
    S = wave_reduce_sum(S);
    if (lane == 0)
        rl[row] = M + logf(S) - logits[(size_t)row * NV + targets[row]];
}

__global__ __launch_bounds__(256) void k_lossreduce(const float* __restrict__ rl,
                                                    float* __restrict__ out_loss) {
    int tid = threadIdx.x;
    float s = 0.f;
    for (int j = tid; j < NM; j += 256) s += rl[j];
    s = wave_reduce_sum(s);
    __shared__ float sv[4];
    int lane = tid & 63, w = tid >> 6;
    if (lane == 0) sv[w] = s;
    __syncthreads();
    if (tid == 0) out_loss[0] = (sv[0] + sv[1] + sv[2] + sv[3]) * (1.0f / NM);
}

extern "C" void kernel_launch(void* const* d_in, const int* in_sizes, int n_in,
                              void* d_out, int out_size, void* d_ws, size_t ws_size,
                              hipStream_t stream) {
    const int* idx      = (const int*)d_in[0];
    const int* targets  = (const int*)d_in[1];
    const float* tok    = (const float*)d_in[2];
    const float* pos    = (const float*)d_in[3];
    const float* wq     = (const float*)d_in[4];
    const float* wk     = (const float*)d_in[5];
    const float* wv     = (const float*)d_in[6];
    const float* wproj  = (const float*)d_in[7];
    const float* bproj  = (const float*)d_in[8];
    const float* ln1_g  = (const float*)d_in[9];
    const float* ln1_b  = (const float*)d_in[10];
    const float* ln2_g  = (const float*)d_in[11];
    const float* ln2_b  = (const float*)d_in[12];
    const float* w1     = (const float*)d_in[13];
    const float* b1     = (const float*)d_in[14];
    const float* w2     = (const float*)d_in[15];
    const float* b2     = (const float*)d_in[16];
    const float* lnf_g  = (const float*)d_in[17];
    const float* lnf_b  = (const float*)d_in[18];
    const float* lm_w   = (const float*)d_in[19];
    const float* lm_b   = (const float*)d_in[20];
    float* out = (float*)d_out;

    char* wsb = (char*)d_ws;
    auto alloc = [&](size_t bytes) { char* p = wsb; wsb += (bytes + 255) & ~(size_t)255; return p; };
    float* x     = (float*)alloc((size_t)NM * ND * 4);
    u16* h_bf    = (u16*)  alloc((size_t)NM * ND * 2);
    float* rl    = (float*)alloc((size_t)NM * 4);
    float* pmax  = (float*)alloc((size_t)NBLK_LM * NM * 4);
    float* psum  = (float*)alloc((size_t)NBLK_LM * NM * 4);
    char* region = (char*)alloc((size_t)NVPAD * ND * 2);   // 103 MB, aliased
    u16* qkv_bf = (u16*)(region);
    u16* vt_bf  = (u16*)(region + ((size_t)12 << 20));
    u16* ob_bf  = (u16*)(region + ((size_t)16 << 20));
    u16* hid_bf = (u16*)(region + ((size_t)20 << 20));
    u16* wqkv_t = (u16*)(region + ((size_t)36 << 20));
    u16* wp_t   = (u16*)(region + ((size_t)42 << 20));
    u16* w1_t   = (u16*)(region + ((size_t)44 << 20));
    u16* w2_t   = (u16*)(region + ((size_t)52 << 20));
    float* p03  = (float*)(region + ((size_t)60 << 20));   // 4 x 8 MB f32 partials
    u16* lm_t   = (u16*)(region);                          // used only after the layer loop

    k_embed<<<NM, 256, 0, stream>>>(idx, tok, pos, x);

    for (int l = 0; l < NL; ++l) {
        const float* wq_l = wq + (size_t)l * NH * ND * 64;
        const float* wk_l = wk + (size_t)l * NH * ND * 64;
        const float* wv_l = wv + (size_t)l * NH * ND * 64;
        const float* wp_l = wproj + (size_t)l * ND * ND;
        const float* bp_l = bproj + (size_t)l * ND;
        const float* w1_l = w1 + (size_t)l * ND * NF;
        const float* b1_l = b1 + (size_t)l * NF;
        const float* w2_l = w2 + (size_t)l * NF * ND;
        const float* b2_l = b2 + (size_t)l * ND;

        k_layernorm<<<NM, 256, 0, stream>>>(x, ln1_g + (size_t)l * ND, ln1_b + (size_t)l * ND, h_bf);

        k_wtrans_all<<<12288, 256, 0, stream>>>(wq_l, wk_l, wv_l, wp_l, w1_l, w2_l,
                                                wqkv_t, wp_t, w1_t, w2_t);

        k_mfma_gemm<false, false, true><<<dim3(16, 24), 256, 0, stream>>>(
            h_bf, wqkv_t, nullptr, nullptr, qkv_bf, ND, 3 * ND, 3 * ND);

        k_vtrans<<<dim3(NT / 64, NB * NH), 256, 0, stream>>>(qkv_bf, vt_bf);
        k_attn_mfma<<<dim3(NT / 64, NB * NH), 256, 0, stream>>>(qkv_bf, vt_bf, ob_bf);

        k_gemm_n64<false, true, false><<<dim3(16, 16), 256, 0, stream>>>(
            ob_bf, wp_t, bp_l, x, x, nullptr, ND, ND);

        k_layernorm<<<NM, 256, 0, stream>>>(x, ln2_g + (size_t)l * ND, ln2_b + (size_t)l * ND, h_bf);

        // MLP1: 256x128 tile, grid 8x32 = 256 blocks
        k_gemm_big<true, false, false, false, true><<<dim3(8, 32), 512, 0, stream>>>(
            h_bf, w1_t, b1_l, nullptr, hid_bf, nullptr, nullptr, ND, ND, NF, NF);

        // MLP2: 256x128 tile, K-split 4 -> grid (8, 8, 4)
        k_gemm_big<false, false, false, true, false><<<dim3(8, 8, 4), 512, 0, stream>>>(
            hid_bf, w2_t, nullptr, p03, nullptr, nullptr, nullptr, NF / 4, NF, ND, ND);
        k_combine4<<<NM, 256, 0, stream>>>(p03, b2_l, x);
    }

    k_layernorm<<<NM, 256, 0, stream>>>(x, lnf_g, lnf_b, h_bf);

    k_wtrans<<<dim3(NVPAD / 32, ND / 32), 256, 0, stream>>>(lm_w, lm_t, ND, NV, NVPAD, NV, NV);
    k_gemm_big<false, true, true, false, false><<<dim3(8, NVPAD / 128), 512, 0, stream>>>(
        h_bf, lm_t, lm_b, out, nullptr, pmax, psum, ND, ND, NV, NV);

    k_losscombine<<<NM / 4, 256, 0, stream>>>(pmax, psum, out, targets, rl);
    k_lossreduce<<<1, 256, 0, stream>>>(rl, out + (size_t)NM * NV);
}

// Round 14
// 1580.139 us; speedup vs baseline: 1.3190x; 1.0202x over previous
//
#include <hip/hip_runtime.h>
#include <cstdint>
#include <cstddef>

typedef unsigned short u16;
typedef unsigned int u32;
typedef __bf16 bf16x8 __attribute__((ext_vector_type(8)));
typedef float f32x4 __attribute__((ext_vector_type(4)));
typedef short short8_t __attribute__((ext_vector_type(8)));

#define NV 50257
#define NVPAD 50304   // 393 * 128
#define NBLK_LM 393
#define ND 1024
#define NT 1024
#define NH 16
#define NL 6
#define NB 2
#define NM 2048       // B*T
#define NF 4096       // 4*D
#define EPSLN 1e-5f

#define VMCNT(n) asm volatile("s_waitcnt vmcnt(" #n ")" ::: "memory")

__device__ __forceinline__ u16 f2bf(float f) {
    unsigned u = __float_as_uint(f);
    return (u16)((u + 0x7fffu + ((u >> 16) & 1u)) >> 16);   // RNE
}
__device__ __forceinline__ float bf2f(u16 h) {
    return __uint_as_float(((unsigned)h) << 16);
}
__device__ __forceinline__ u32 pack2bf(float lo, float hi) {
    return (u32)f2bf(lo) | ((u32)f2bf(hi) << 16);
}

__device__ __forceinline__ void gload_lds16(const u16* g, u16* l) {
    __builtin_amdgcn_global_load_lds((const __attribute__((address_space(1))) void*)g,
                                     (__attribute__((address_space(3))) void*)l, 16, 0, 0);
}

__device__ __forceinline__ float wave_reduce_sum(float v) {
#pragma unroll
    for (int off = 32; off >= 1; off >>= 1) v += __shfl_xor(v, off, 64);
    return v;
}

// ---------------- embedding ----------------
__global__ __launch_bounds__(256) void k_embed(const int* __restrict__ idx,
                                               const float* __restrict__ tok,
                                               const float* __restrict__ pos,
                                               float* __restrict__ x) {
    int m = blockIdx.x;
    int t = m & (NT - 1);
    int tokid = idx[m];
    int d = threadIdx.x * 4;
    float4 a = *(const float4*)(tok + (size_t)tokid * ND + d);
    float4 p = *(const float4*)(pos + (size_t)t * ND + d);
    a.x += p.x; a.y += p.y; a.z += p.z; a.w += p.w;
    *(float4*)(x + (size_t)m * ND + d) = a;
}

// ---------------- layernorm ----------------
__global__ __launch_bounds__(256) void k_layernorm(const float* __restrict__ x,
                                                   const float* __restrict__ g,
                                                   const float* __restrict__ b,
                                                   u16* __restrict__ outb) {
    int m = blockIdx.x;
    int d = threadIdx.x * 4;
    const float4 v = *(const float4*)(x + (size_t)m * ND + d);
    float s = v.x + v.y + v.z + v.w;
    float q = v.x * v.x + v.y * v.y + v.z * v.z + v.w * v.w;
    s = wave_reduce_sum(s);
    q = wave_reduce_sum(q);
    __shared__ float ss[4], sq[4];
    int lane = threadIdx.x & 63, w = threadIdx.x >> 6;
    if (lane == 0) { ss[w] = s; sq[w] = q; }
    __syncthreads();
    s = ss[0] + ss[1] + ss[2] + ss[3];
    q = sq[0] + sq[1] + sq[2] + sq[3];
    float mu = s * (1.0f / ND);
    float var = q * (1.0f / ND) - mu * mu;
    float rstd = rsqrtf(var + EPSLN);
    float4 gg = *(const float4*)(g + d);
    float4 bb = *(const float4*)(b + d);
    ushort4 pk;
    pk.x = f2bf((v.x - mu) * rstd * gg.x + bb.x);
    pk.y = f2bf((v.y - mu) * rstd * gg.y + bb.y);
    pk.z = f2bf((v.z - mu) * rstd * gg.z + bb.z);
    pk.w = f2bf((v.w - mu) * rstd * gg.w + bb.w);
    *(ushort4*)(outb + (size_t)m * ND + d) = pk;
}

// ---------------- LM weight transpose + f32->bf16 (N-padded) ----------------
__global__ __launch_bounds__(256) void k_wtrans(const float* __restrict__ W,
                                                u16* __restrict__ Wt,
                                                int K, int N, int Npad, int hs, int ld) {
    __shared__ float t[32][33];
    const int nb = blockIdx.x << 5, kb = blockIdx.y << 5;
    const int tx = threadIdx.x & 31, tq = threadIdx.x >> 5;
    const int n = nb + tx;
    if (n < N) {
        const int head = n / hs, nc = n - head * hs;
        const float* src = W + (size_t)head * K * hs + nc;
#pragma unroll
        for (int i = 0; i < 4; ++i)
            t[(tq << 2) + i][tx] = src[(size_t)(kb + (tq << 2) + i) * ld];
    } else {
#pragma unroll
        for (int i = 0; i < 4; ++i) t[(tq << 2) + i][tx] = 0.f;
    }
    __syncthreads();
#pragma unroll
    for (int i = 0; i < 4; ++i) {
        const int nn = nb + (tq << 2) + i;
        if (nn < Npad) Wt[(size_t)nn * K + kb + tx] = f2bf(t[tx][(tq << 2) + i]);
    }
}

// ---------------- fused per-layer weight transpose (qkv + wp + w1 + w2) ----------------
__global__ __launch_bounds__(256) void k_wtrans_all(const float* __restrict__ Wq,
                                                    const float* __restrict__ Wk,
                                                    const float* __restrict__ Wv,
                                                    const float* __restrict__ Wp,
                                                    const float* __restrict__ W1,
                                                    const float* __restrict__ W2,
                                                    u16* __restrict__ Wqkvt,
                                                    u16* __restrict__ Wpt,
                                                    u16* __restrict__ W1t,
                                                    u16* __restrict__ W2t) {
    __shared__ float t[32][33];
    int bid = blockIdx.x;
    const int tx = threadIdx.x & 31, tq = threadIdx.x >> 5;
    if (bid < 3072) {
        const int z = bid >> 10;
        const float* W = (z == 0) ? Wq : (z == 1) ? Wk : Wv;
        u16* dst = Wqkvt + (size_t)z * ND * ND;
        bid &= 1023;
        const int nb = (bid & 31) << 5, kb = (bid >> 5) << 5;
        const int n = nb + tx;
        const int head = n >> 6, nc = n & 63;
        const float* src = W + (size_t)head * ND * 64 + nc;
#pragma unroll
        for (int i = 0; i < 4; ++i)
            t[(tq << 2) + i][tx] = src[(size_t)(kb + (tq << 2) + i) * 64];
        __syncthreads();
#pragma unroll
        for (int i = 0; i < 4; ++i)
            dst[(size_t)(nb + (tq << 2) + i) * ND + kb + tx] = f2bf(t[tx][(tq << 2) + i]);
        return;
    }
    const float* W; u16* Wt; int K, N, nb, kb;
    if (bid < 4096)      { W = Wp; Wt = Wpt; K = ND; N = ND; bid -= 3072;
                           nb = (bid & 31) << 5; kb = (bid >> 5) << 5; }
    else if (bid < 8192) { W = W1; Wt = W1t; K = ND; N = NF; bid -= 4096;
                           nb = (bid & 127) << 5; kb = (bid >> 7) << 5; }
    else                 { W = W2; Wt = W2t; K = NF; N = ND; bid -= 8192;
                           nb = (bid & 31) << 5; kb = (bid >> 5) << 5; }
#pragma unroll
    for (int i = 0; i < 4; ++i)
        t[(tq << 2) + i][tx] = W[(size_t)(kb + (tq << 2) + i) * N + nb + tx];
    __syncthreads();
#pragma unroll
    for (int i = 0; i < 4; ++i)
        Wt[(size_t)(nb + (tq << 2) + i) * K + kb + tx] = f2bf(t[tx][(tq << 2) + i]);
}

// ---------------- V transpose: qkv[B,T,3072] -> vt[B,H,64,T] (bf16) ----------------
__global__ __launch_bounds__(256) void k_vtrans(const u16* __restrict__ qkv,
                                                u16* __restrict__ vt) {
    __shared__ u16 L[64][72];
    const int tt = blockIdx.x, bh = blockIdx.y;
    const int b = bh >> 4, h = bh & 15;
    const int tid = threadIdx.x;
    const int tr = tid >> 2, dc = (tid & 3) << 4;
    const u16* src = qkv + (size_t)(b * NT + tt * 64 + tr) * 3072 + 2048 + h * 64 + dc;
    short8_t v0 = *(const short8_t*)src;
    short8_t v1 = *(const short8_t*)(src + 8);
#pragma unroll
    for (int j = 0; j < 8; ++j) { L[tr][dc + j] = (u16)v0[j]; L[tr][dc + 8 + j] = (u16)v1[j]; }
    __syncthreads();
    const int dr = tid >> 2, tc = (tid & 3) << 4;
    union { u16 us[16]; short8_t v[2]; } tmp;
#pragma unroll
    for (int j = 0; j < 16; ++j) tmp.us[j] = L[tc + j][dr];
    u16* dst = vt + ((size_t)bh * 64 + dr) * NT + tt * 64 + tc;
    *(short8_t*)dst = tmp.v[0];
    *(short8_t*)(dst + 8) = tmp.v[1];
}

// =====================================================================================
// 256x128-tile 2-phase MFMA GEMM with COUNTED vmcnt barriers: tile t+1's loads stay
// in flight across the barrier (wait only for tile t, issued a full step earlier).
// {STG(t+1); VMCNT(3); bar; ds_read+MFMA; bar}. Same LDS/occupancy as the proven R11.
// =====================================================================================
template <bool RELU, bool NBOUND, bool PART, bool KSPLIT, bool OUTBF16>
__global__ __launch_bounds__(512) void k_gemm_big(
    const u16* __restrict__ A, const u16* __restrict__ Bt,
    const float* __restrict__ bias,
    float* __restrict__ Cf, u16* __restrict__ Cb,
    float* __restrict__ pmax_g, float* __restrict__ psum_g,
    int Ksub, int Ktot, int N, int ldc)
{
    __shared__ u16 As[2][256 * 32];
    __shared__ u16 Bs[2][128 * 32];
    const int lin = blockIdx.y * (int)gridDim.x + blockIdx.x;
    const int nwg = (int)gridDim.x * (int)gridDim.y;   // % 8 == 0 for all our shapes
    const int cpx = nwg >> 3;
    const int swz = (lin & 7) * cpx + (lin >> 3);
    const int m0 = (swz & 7) * 256;
    const int n0 = (swz >> 3) * 128;
    const int tid = threadIdx.x;
    const int lane = tid & 63, w = tid >> 6;  // 8 waves
    const int wr = w >> 1, wc = w & 1;        // 4 x 2
    const int lr = lane & 15, kg = lane >> 4;

    const int srow = lane >> 2;
    const int scol = (((lane & 3) ^ ((lane >> 3) & 3)) << 3);   // chunk ^ ((row>>1)&3)
    const int koff = KSPLIT ? (int)blockIdx.z * Ksub : 0;
    const u16* gA0 = A + (size_t)(m0 + w * 16 + srow) * Ktot + koff + scol;
    const u16* gA1 = gA0 + (size_t)128 * Ktot;
    const u16* gB0 = Bt + (size_t)(n0 + w * 16 + srow) * Ktot + koff + scol;

    f32x4 acc[4][4] = {};
    const int nt = Ksub >> 5;

    gload_lds16(gA0, &As[0][w * 512]);
    gload_lds16(gA1, &As[0][4096 + w * 512]);
    gload_lds16(gB0, &Bs[0][w * 512]);

    int cur = 0;
    for (int t = 0; t < nt; ++t) {
        if (t + 1 < nt) {
            const int ko = (t + 1) << 5;
            gload_lds16(gA0 + ko, &As[cur ^ 1][w * 512]);
            gload_lds16(gA1 + ko, &As[cur ^ 1][4096 + w * 512]);
            gload_lds16(gB0 + ko, &Bs[cur ^ 1][w * 512]);
            VMCNT(3);                       // tile t complete; t+1 stays in flight
        } else {
            VMCNT(0);
        }
        __builtin_amdgcn_s_barrier();
        bf16x8 af[4], bfr[4];
        const int rsw = ((kg ^ ((lr >> 1) & 3)) << 3);
#pragma unroll
        for (int mi = 0; mi < 4; ++mi)
            af[mi] = *(const bf16x8*)&As[cur][(wr * 64 + mi * 16 + lr) * 32 + rsw];
#pragma unroll
        for (int ni = 0; ni < 4; ++ni)
            bfr[ni] = *(const bf16x8*)&Bs[cur][(wc * 64 + ni * 16 + lr) * 32 + rsw];
#pragma unroll
        for (int mi = 0; mi < 4; ++mi)
#pragma unroll
            for (int ni = 0; ni < 4; ++ni)
                acc[mi][ni] = __builtin_amdgcn_mfma_f32_16x16x32_bf16(af[mi], bfr[ni], acc[mi][ni], 0, 0, 0);
        __builtin_amdgcn_s_barrier();       // reads of buf[cur] retired before overwrite
        cur ^= 1;
    }

    float* Cz = KSPLIT ? (Cf + (size_t)blockIdx.z * NM * ldc) : Cf;
#pragma unroll
    for (int mi = 0; mi < 4; ++mi)
#pragma unroll
        for (int ni = 0; ni < 4; ++ni)
#pragma unroll
            for (int r = 0; r < 4; ++r) {
                const int row = m0 + wr * 64 + mi * 16 + kg * 4 + r;
                const int col = n0 + wc * 64 + ni * 16 + lr;
                if (NBOUND && col >= N) continue;
                float c = acc[mi][ni][r];
                if (bias) c += bias[col];
                if (RELU) c = fmaxf(c, 0.f);
                if (PART) acc[mi][ni][r] = c;   // keep biased value for partials
                if (OUTBF16) Cb[(size_t)row * ldc + col] = f2bf(c);
                else         Cz[(size_t)row * ldc + col] = c;
            }

    if constexpr (PART) {
        float* redm = (float*)As;            // [2][256]
        float* reds = redm + 512;            // [2][256]
#pragma unroll
        for (int mi = 0; mi < 4; ++mi)
#pragma unroll
            for (int r = 0; r < 4; ++r) {
                float vmax = -3.0e38f;
#pragma unroll
                for (int ni = 0; ni < 4; ++ni) {
                    const int col = n0 + wc * 64 + ni * 16 + lr;
                    vmax = fmaxf(vmax, (col < N) ? acc[mi][ni][r] : -3.0e38f);
                }
                vmax = fmaxf(vmax, __shfl_xor(vmax, 1));
                vmax = fmaxf(vmax, __shfl_xor(vmax, 2));
                vmax = fmaxf(vmax, __shfl_xor(vmax, 4));
                vmax = fmaxf(vmax, __shfl_xor(vmax, 8));
                if (lr == 0) redm[wc * 256 + wr * 64 + mi * 16 + kg * 4 + r] = vmax;
            }
        __syncthreads();
#pragma unroll
        for (int mi = 0; mi < 4; ++mi)
#pragma unroll
            for (int r = 0; r < 4; ++r) {
                const int rloc = wr * 64 + mi * 16 + kg * 4 + r;
                const float M = fmaxf(redm[rloc], redm[256 + rloc]);
                float s = 0.f;
#pragma unroll
                for (int ni = 0; ni < 4; ++ni) {
                    const int col = n0 + wc * 64 + ni * 16 + lr;
                    if (col < N) s += __expf(acc[mi][ni][r] - M);
                }
                s += __shfl_xor(s, 1);
                s += __shfl_xor(s, 2);
                s += __shfl_xor(s, 4);
                s += __shfl_xor(s, 8);
                if (lr == 0) reds[wc * 256 + rloc] = s;
            }
        __syncthreads();
        if (tid < 256) {
            const float M = fmaxf(redm[tid], redm[256 + tid]);
            const float S = reds[tid] + reds[256 + tid];
            const int nblk = n0 >> 7;
            pmax_g[(size_t)nblk * NM + m0 + tid] = M;
            psum_g[(size_t)nblk * NM + m0 + tid] = S;
        }
    }
}

// ---------------- 128x128 2-phase MFMA GEMM (QKV), counted vmcnt ----------------
template <bool RELU, bool NBOUND, bool OUTBF16>
__global__ __launch_bounds__(256) void k_mfma_gemm(
    const u16* __restrict__ A, const u16* __restrict__ Bt,
    const float* __restrict__ bias,
    float* __restrict__ Cf, u16* __restrict__ Cb,
    int K, int N, int ldc)
{
    __shared__ u16 As[2][128 * 32];
    __shared__ u16 Bs[2][128 * 32];
    const int lin = blockIdx.y * 16 + blockIdx.x;
    const int nwg = (int)gridDim.y * 16;
    const int cpx = nwg >> 3;
    const int swz = (lin & 7) * cpx + (lin >> 3);
    const int m0 = (swz & 15) * 128;
    const int n0 = (swz >> 4) * 128;
    const int tid = threadIdx.x;
    const int lane = tid & 63, wv = tid >> 6;
    const int wr = wv >> 1, wc = wv & 1;
    const int lr = lane & 15, kg = lane >> 4;

    const int srow = lane >> 2;
    const int scol = (((lane & 3) ^ ((lane >> 3) & 3)) << 3);
    const u16* gA0 = A + (size_t)(m0 + wv * 16 + srow) * K + scol;
    const u16* gA1 = gA0 + (size_t)64 * K;
    const u16* gB0 = Bt + (size_t)(n0 + wv * 16 + srow) * K + scol;
    const u16* gB1 = gB0 + (size_t)64 * K;

    f32x4 acc[4][4] = {};
    const int nt = K >> 5;

    gload_lds16(gA0, &As[0][wv * 512]);
    gload_lds16(gA1, &As[0][2048 + wv * 512]);
    gload_lds16(gB0, &Bs[0][wv * 512]);
    gload_lds16(gB1, &Bs[0][2048 + wv * 512]);

    int cur = 0;
    for (int t = 0; t < nt; ++t) {
        if (t + 1 < nt) {
            const int ko = (t + 1) << 5;
            gload_lds16(gA0 + ko, &As[cur ^ 1][wv * 512]);
            gload_lds16(gA1 + ko, &As[cur ^ 1][2048 + wv * 512]);
            gload_lds16(gB0 + ko, &Bs[cur ^ 1][wv * 512]);
            gload_lds16(gB1 + ko, &Bs[cur ^ 1][2048 + wv * 512]);
            VMCNT(4);
        } else {
            VMCNT(0);
        }
        __builtin_amdgcn_s_barrier();
        bf16x8 af[4], bfr[4];
        const int rsw = ((kg ^ ((lr >> 1) & 3)) << 3);
#pragma unroll
        for (int mi = 0; mi < 4; ++mi) {
            const int R = wr * 64 + mi * 16 + lr;
            af[mi] = *(const bf16x8*)&As[cur][R * 32 + rsw];
        }
#pragma unroll
        for (int ni = 0; ni < 4; ++ni) {
            const int R = wc * 64 + ni * 16 + lr;
            bfr[ni] = *(const bf16x8*)&Bs[cur][R * 32 + rsw];
        }
#pragma unroll
        for (int mi = 0; mi < 4; ++mi)
#pragma unroll
            for (int ni = 0; ni < 4; ++ni)
                acc[mi][ni] = __builtin_amdgcn_mfma_f32_16x16x32_bf16(af[mi], bfr[ni], acc[mi][ni], 0, 0, 0);
        __builtin_amdgcn_s_barrier();
        cur ^= 1;
    }
#pragma unroll
    for (int mi = 0; mi < 4; ++mi) {
#pragma unroll
        for (int ni = 0; ni < 4; ++ni) {
#pragma unroll
            for (int r = 0; r < 4; ++r) {
                const int row = m0 + wr * 64 + mi * 16 + kg * 4 + r;
                const int col = n0 + wc * 64 + ni * 16 + lr;
                if (NBOUND && col >= N) continue;
                float c = acc[mi][ni][r];
                if (bias) c += bias[col];
                if (RELU) c = fmaxf(c, 0.f);
                if (OUTBF16) Cb[(size_t)row * ldc + col] = f2bf(c);
                else         Cf[(size_t)row * ldc + col] = c;
            }
        }
    }
}

// ---------------- combine: x += p0+p1+p2+p3 + bias ----------------
__global__ __launch_bounds__(256) void k_combine4(const float* __restrict__ p,
                                                  const float* __restrict__ bias,
                                                  float* __restrict__ x) {
    const int m = blockIdx.x;
    const int d = threadIdx.x * 4;
    const size_t off = (size_t)m * ND + d;
    float4 a  = *(const float4*)(x + off);
    float4 q0 = *(const float4*)(p + off);
    float4 q1 = *(const float4*)(p + (size_t)NM * ND + off);
    float4 q2 = *(const float4*)(p + (size_t)2 * NM * ND + off);
    float4 q3 = *(const float4*)(p + (size_t)3 * NM * ND + off);
    float4 bb = *(const float4*)(bias + d);
    a.x += ((q0.x + q1.x) + (q2.x + q3.x)) + bb.x;
    a.y += ((q0.y + q1.y) + (q2.y + q3.y)) + bb.y;
    a.z += ((q0.z + q1.z) + (q2.z + q3.z)) + bb.z;
    a.w += ((q0.w + q1.w) + (q2.w + q3.w)) + bb.w;
    *(float4*)(x + off) = a;
}

// ---------------- 128x64-tile MFMA GEMM (proj), counted vmcnt --------
template <bool RELU, bool RESID, bool OUTBF16>
__global__ __launch_bounds__(256) void k_gemm_n64(
    const u16* __restrict__ A, const u16* __restrict__ Bt,
    const float* __restrict__ bias, const float* __restrict__ resid,
    float* __restrict__ Cf, u16* __restrict__ Cb,
    int K, int ldc)
{
    __shared__ u16 As[2][128 * 32];
    __shared__ u16 Bs[2][64 * 32];
    const int lin = blockIdx.y * 16 + blockIdx.x;
    const int nwg = (int)gridDim.y * 16;
    const int cpx = nwg >> 3;
    const int swz = (lin & 7) * cpx + (lin >> 3);
    const int m0 = (swz & 15) * 128;
    const int n0 = (swz >> 4) * 64;
    const int tid = threadIdx.x;
    const int lane = tid & 63, wv = tid >> 6;
    const int lr = lane & 15, kg = lane >> 4;

    const int srow = lane >> 2;
    const int scol = (((lane & 3) ^ ((lane >> 3) & 3)) << 3);
    const u16* gA0 = A + (size_t)(m0 + wv * 32 + srow) * K + scol;
    const u16* gA1 = gA0 + (size_t)16 * K;
    const u16* gB0 = Bt + (size_t)(n0 + wv * 16 + srow) * K + scol;

    f32x4 acc[2][4] = {};
    const int nt = K >> 5;

    gload_lds16(gA0, &As[0][wv * 1024]);
    gload_lds16(gA1, &As[0][wv * 1024 + 512]);
    gload_lds16(gB0, &Bs[0][wv * 512]);

    int cur = 0;
    for (int t = 0; t < nt; ++t) {
        if (t + 1 < nt) {
            const int ko = (t + 1) << 5;
            gload_lds16(gA0 + ko, &As[cur ^ 1][wv * 1024]);
            gload_lds16(gA1 + ko, &As[cur ^ 1][wv * 1024 + 512]);
            gload_lds16(gB0 + ko, &Bs[cur ^ 1][wv * 512]);
            VMCNT(3);
        } else {
            VMCNT(0);
        }
        __builtin_amdgcn_s_barrier();
        bf16x8 af[2], bfr[4];
        const int rsw = ((kg ^ ((lr >> 1) & 3)) << 3);
#pragma unroll
        for (int mi = 0; mi < 2; ++mi)
            af[mi] = *(const bf16x8*)&As[cur][(wv * 32 + mi * 16 + lr) * 32 + rsw];
#pragma unroll
        for (int ni = 0; ni < 4; ++ni)
            bfr[ni] = *(const bf16x8*)&Bs[cur][(ni * 16 + lr) * 32 + rsw];
#pragma unroll
        for (int mi = 0; mi < 2; ++mi)
#pragma unroll
            for (int ni = 0; ni < 4; ++ni)
                acc[mi][ni] = __builtin_amdgcn_mfma_f32_16x16x32_bf16(af[mi], bfr[ni], acc[mi][ni], 0, 0, 0);
        __builtin_amdgcn_s_barrier();
        cur ^= 1;
    }
#pragma unroll
    for (int mi = 0; mi < 2; ++mi) {
#pragma unroll
        for (int ni = 0; ni < 4; ++ni) {
#pragma unroll
            for (int r = 0; r < 4; ++r) {
                const int row = m0 + wv * 32 + mi * 16 + kg * 4 + r;
                const int col = n0 + ni * 16 + lr;
                float c = acc[mi][ni][r];
                if (bias) c += bias[col];
                if (RELU) c = fmaxf(c, 0.f);
                if (RESID) c += resid[(size_t)row * ldc + col];
                if (OUTBF16) Cb[(size_t)row * ldc + col] = f2bf(c);
                else         Cf[(size_t)row * ldc + col] = c;
            }
        }
    }
}

// ---------------- MFMA flash attention: 3-buffer KV pipeline, counted vmcnt ----------
__global__ __launch_bounds__(256) void k_attn_mfma(const u16* __restrict__ qkv,
                                                   const u16* __restrict__ vt,
                                                   u16* __restrict__ ob) {
    const int qt = (blockIdx.y < 16) ? (int)blockIdx.x : 15 - (int)blockIdx.x;
    const int bh = blockIdx.y;
    const int b = bh >> 4, h = bh & 15;
    const int tid = threadIdx.x;
    const int lane = tid & 63, w = tid >> 6;
    const int lr = lane & 15, kg = lane >> 4;

    __shared__ u16 Qs[64 * 64];
    __shared__ u16 Ks[3][64 * 64];
    __shared__ u16 Vs[3][64 * 64];

    const int srow8 = lane >> 3;
    const int csw = ((lane & 7) ^ srow8) << 3;

    {
        const int r0 = w * 8 + srow8;
        gload_lds16(qkv + (size_t)(b * NT + qt * 64 + r0) * 3072 + h * 64 + csw, &Qs[w * 512]);
        gload_lds16(qkv + (size_t)(b * NT + qt * 64 + 32 + r0) * 3072 + h * 64 + csw, &Qs[2048 + w * 512]);
    }
#define STAGE_KV(bb, st)                                                                            \
    {                                                                                               \
        const int r0_ = w * 8 + srow8;                                                              \
        gload_lds16(qkv + (size_t)(b * NT + (st) * 64 + r0_) * 3072 + 1024 + h * 64 + csw,          \
                    &Ks[bb][w * 512]);                                                              \
        gload_lds16(qkv + (size_t)(b * NT + (st) * 64 + 32 + r0_) * 3072 + 1024 + h * 64 + csw,     \
                    &Ks[bb][2048 + w * 512]);                                                       \
        gload_lds16(vt + ((size_t)bh * 64 + r0_) * NT + (st) * 64 + csw, &Vs[bb][w * 512]);         \
        gload_lds16(vt + ((size_t)bh * 64 + 32 + r0_) * NT + (st) * 64 + csw,                       \
                    &Vs[bb][2048 + w * 512]);                                                       \
    }
    STAGE_KV(0, 0);
    if (qt >= 1) STAGE_KV(1, 1);
    if (qt == 0) { VMCNT(0); } else { VMCNT(4); }
    __builtin_amdgcn_s_barrier();

    bf16x8 qf[2];
    {
        const int qrow = w * 16 + lr;
#pragma unroll
        for (int ds_ = 0; ds_ < 2; ++ds_)
            qf[ds_] = *(const bf16x8*)&Qs[qrow * 64 + ((((ds_ << 2) + kg) ^ (lr & 7)) << 3)];
    }

    float mstate = -3.0e38f, lstate = 0.f;
    f32x4 acc_o[4] = {};
    const int qg = qt * 64 + w * 16 + lr;

    int cur = 0;
    for (int st = 0; st <= qt; ++st) {
        if (st > 0) {
            if (st < qt) { VMCNT(4); } else { VMCNT(0); }
            __builtin_amdgcn_s_barrier();
        }
        if (st + 2 <= qt) {
            int tgt = cur + 2; if (tgt >= 3) tgt -= 3;
            STAGE_KV(tgt, st + 2);
        }
        const bool diag = (st == qt);
        const int milim = diag ? w : 3;

        f32x4 acc_s[4] = {};
#pragma unroll
        for (int mi = 0; mi < 4; ++mi) {
            if (mi <= milim) {
                const int srw = mi * 16 + lr;
#pragma unroll
                for (int ds_ = 0; ds_ < 2; ++ds_) {
                    bf16x8 kf = *(const bf16x8*)&Ks[cur][srw * 64 + ((((ds_ << 2) + kg) ^ (lr & 7)) << 3)];
                    acc_s[mi] = __builtin_amdgcn_mfma_f32_16x16x32_bf16(kf, qf[ds_], acc_s[mi], 0, 0, 0);
                }
            }
        }
        float tilemax = -3.0e38f;
#pragma unroll
        for (int mi = 0; mi < 4; ++mi)
#pragma unroll
            for (int r = 0; r < 4; ++r) {
                float x_ = acc_s[mi][r] * 0.125f;
                const int sg = st * 64 + mi * 16 + kg * 4 + r;
                if (mi > milim || sg > qg) x_ = -3.0e38f;
                acc_s[mi][r] = x_;
                tilemax = fmaxf(tilemax, x_);
            }
        tilemax = fmaxf(tilemax, __shfl_xor(tilemax, 16));
        tilemax = fmaxf(tilemax, __shfl_xor(tilemax, 32));
        const float mnew = fmaxf(mstate, tilemax);
        const float rfac = __expf(mstate - mnew);
        mstate = mnew;

        float psum = 0.f;
        u32 pk[4][2];
#pragma unroll
        for (int mi = 0; mi < 4; ++mi) {
            float p0 = __expf(acc_s[mi][0] - mnew);
            float p1 = __expf(acc_s[mi][1] - mnew);
            float p2 = __expf(acc_s[mi][2] - mnew);
            float p3 = __expf(acc_s[mi][3] - mnew);
            psum += p0 + p1 + p2 + p3;
            pk[mi][0] = pack2bf(p0, p1);
            pk[mi][1] = pack2bf(p2, p3);
        }
        psum += __shfl_xor(psum, 16);
        psum += __shfl_xor(psum, 32);
        lstate = lstate * rfac + psum;

        float rf[4];
#pragma unroll
        for (int r = 0; r < 4; ++r) rf[r] = __shfl(rfac, kg * 4 + r);
#pragma unroll
        for (int ni = 0; ni < 4; ++ni)
#pragma unroll
            for (int r = 0; r < 4; ++r) acc_o[ni][r] *= rf[r];

        const int src0 = ((kg & 1) << 5) + lr;
        const int src1 = src0 + 16;
#pragma unroll
        for (int ks_ = 0; ks_ < 2; ++ks_) {
            const u32 lo_a = __shfl((int)pk[ks_ * 2][0], src0);
            const u32 lo_b = __shfl((int)pk[ks_ * 2][1], src0);
            const u32 lo_c = __shfl((int)pk[ks_ * 2][0], src1);
            const u32 lo_d = __shfl((int)pk[ks_ * 2][1], src1);
            const u32 hi_a = __shfl((int)pk[ks_ * 2 + 1][0], src0);
            const u32 hi_b = __shfl((int)pk[ks_ * 2 + 1][1], src0);
            const u32 hi_c = __shfl((int)pk[ks_ * 2 + 1][0], src1);
            const u32 hi_d = __shfl((int)pk[ks_ * 2 + 1][1], src1);
            union { u32 u[4]; bf16x8 v; } pa;
            pa.u[0] = (kg & 2) ? hi_a : lo_a;
            pa.u[1] = (kg & 2) ? hi_b : lo_b;
            pa.u[2] = (kg & 2) ? hi_c : lo_c;
            pa.u[3] = (kg & 2) ? hi_d : lo_d;
#pragma unroll
            for (int ni = 0; ni < 4; ++ni) {
                const int drow = ni * 16 + lr;
                bf16x8 vf = *(const bf16x8*)&Vs[cur][drow * 64 + ((((ks_ << 2) + kg) ^ (lr & 7)) << 3)];
                acc_o[ni] = __builtin_amdgcn_mfma_f32_16x16x32_bf16(pa.v, vf, acc_o[ni], 0, 0, 0);
            }
        }
        cur = (cur == 2) ? 0 : cur + 1;
    }

    float il[4];
#pragma unroll
    for (int r = 0; r < 4; ++r) il[r] = 1.0f / __shfl(lstate, kg * 4 + r);
#pragma unroll
    for (int ni = 0; ni < 4; ++ni)
#pragma unroll
        for (int r = 0; r < 4; ++r) {
            const int q2 = qt * 64 + w * 16 + kg * 4 + r;
            ob[(size_t)(b * NT + q2) * ND + h * 64 + ni * 16 + lr] = f2bf(acc_o[ni][r] * il[r]);
        }
#undef STAGE_KV
}

// ---------------- loss combine from per-block partials ([nblk][NM]) ----------------
__global__ __launch_bounds__(256) void k_losscombine(const float* __restrict__ pmax,
                                                     const float* __restrict__ psum,
                                                     const float* __restrict__ logits,
                                                     const int* __restrict__ targets,
                                                     float* __restrict__ rl) {
    const int row = blockIdx.x * 4 + (threadIdx.x >> 6);
    const int lane = threadIdx.x & 63;
    float M = -3.0e38f;
    for (int j = lane; j < NBLK_LM; j += 64) M = fmaxf(M, pmax[(size_t)j * NM + row]);
#pragma unroll
    for (int off = 32; off >= 1; off >>= 1) M = fmaxf(M, __shfl_xor(M, off, 64));
    float S = 0.f;
    for (int j = lane; j < NBLK_LM; j += 64)
        S += psum[(size_t)j * NM + row] * __expf(pmax[(size_t)j * NM + row] - M);
    S = wave_reduce_sum(S);
    if (lane == 0)
        rl[row] = M + logf(S) - logits[(size_t)row * NV + targets[row]];
}

__global__ __launch_bounds__(256) void k_lossreduce(const float* __restrict__ rl,
                                                    float* __restrict__ out_loss) {
    int tid = threadIdx.x;
    float s = 0.f;
    for (int j = tid; j < NM; j += 256) s += rl[j];
    s = wave_reduce_sum(s);
    __shared__ float sv[4];
    int lane = tid & 63, w = tid >> 6;
    if (lane == 0) sv[w] = s;
    __syncthreads();
    if (tid == 0) out_loss[0] = (sv[0] + sv[1] + sv[2] + sv[3]) * (1.0f / NM);
}

extern "C" void kernel_launch(void* const* d_in, const int* in_sizes, int n_in,
                              void* d_out, int out_size, void* d_ws, size_t ws_size,
                              hipStream_t stream) {
    const int* idx      = (const int*)d_in[0];
    const int* targets  = (const int*)d_in[1];
    const float* tok    = (const float*)d_in[2];
    const float* pos    = (const float*)d_in[3];
    const float* wq     = (const float*)d_in[4];
    const float* wk     = (const float*)d_in[5];
    const float* wv     = (const float*)d_in[6];
    const float* wproj  = (const float*)d_in[7];
    const float* bproj  = (const float*)d_in[8];
    const float* ln1_g  = (const float*)d_in[9];
    const float* ln1_b  = (const float*)d_in[10];
    const float* ln2_g  = (const float*)d_in[11];
    const float* ln2_b  = (const float*)d_in[12];
    const float* w1     = (const float*)d_in[13];
    const float* b1     = (const float*)d_in[14];
    const float* w2     = (const float*)d_in[15];
    const float* b2     = (const float*)d_in[16];
    const float* lnf_g  = (const float*)d_in[17];
    const float* lnf_b  = (const float*)d_in[18];
    const float* lm_w   = (const float*)d_in[19];
    const float* lm_b   = (const float*)d_in[20];
    float* out = (float*)d_out;

    char* wsb = (char*)d_ws;
    auto alloc = [&](size_t bytes) { char* p = wsb; wsb += (bytes + 255) & ~(size_t)255; return p; };
    float* x     = (float*)alloc((size_t)NM * ND * 4);
    u16* h_bf    = (u16*)  alloc((size_t)NM * ND * 2);
    float* rl    = (float*)alloc((size_t)NM * 4);
    float* pmax  = (float*)alloc((size_t)NBLK_LM * NM * 4);
    float* psum  = (float*)alloc((size_t)NBLK_LM * NM * 4);
    char* region = (char*)alloc((size_t)NVPAD * ND * 2);   // 103 MB, aliased
    u16* qkv_bf = (u16*)(region);
    u16* vt_bf  = (u16*)(region + ((size_t)12 << 20));
    u16* ob_bf  = (u16*)(region + ((size_t)16 << 20));
    u16* hid_bf = (u16*)(region + ((size_t)20 << 20));
    u16* wqkv_t = (u16*)(region + ((size_t)36 << 20));
    u16* wp_t   = (u16*)(region + ((size_t)42 << 20));
    u16* w1_t   = (u16*)(region + ((size_t)44 << 20));
    u16* w2_t   = (u16*)(region + ((size_t)52 << 20));
    float* p03  = (float*)(region + ((size_t)60 << 20));   // 4 x 8 MB f32 partials
    u16* lm_t   = (u16*)(region);                          // used only after the layer loop

    k_embed<<<NM, 256, 0, stream>>>(idx, tok, pos, x);

    for (int l = 0; l < NL; ++l) {
        const float* wq_l = wq + (size_t)l * NH * ND * 64;
        const float* wk_l = wk + (size_t)l * NH * ND * 64;
        const float* wv_l = wv + (size_t)l * NH * ND * 64;
        const float* wp_l = wproj + (size_t)l * ND * ND;
        const float* bp_l = bproj + (size_t)l * ND;
        const float* w1_l = w1 + (size_t)l * ND * NF;
        const float* b1_l = b1 + (size_t)l * NF;
        const float* w2_l = w2 + (size_t)l * NF * ND;
        const float* b2_l = b2 + (size_t)l * ND;

        k_layernorm<<<NM, 256, 0, stream>>>(x, ln1_g + (size_t)l * ND, ln1_b + (size_t)l * ND, h_bf);

        k_wtrans_all<<<12288, 256, 0, stream>>>(wq_l, wk_l, wv_l, wp_l, w1_l, w2_l,
                                                wqkv_t, wp_t, w1_t, w2_t);

        k_mfma_gemm<false, false, true><<<dim3(16, 24), 256, 0, stream>>>(
            h_bf, wqkv_t, nullptr, nullptr, qkv_bf, ND, 3 * ND, 3 * ND);

        k_vtrans<<<dim3(NT / 64, NB * NH), 256, 0, stream>>>(qkv_bf, vt_bf);
        k_attn_mfma<<<dim3(NT / 64, NB * NH), 256, 0, stream>>>(qkv_bf, vt_bf, ob_bf);

        k_gemm_n64<false, true, false><<<dim3(16, 16), 256, 0, stream>>>(
            ob_bf, wp_t, bp_l, x, x, nullptr, ND, ND);

        k_layernorm<<<NM, 256, 0, stream>>>(x, ln2_g + (size_t)l * ND, ln2_b + (size_t)l * ND, h_bf);

        // MLP1: 256x128 tile, grid 8x32 = 256 blocks
        k_gemm_big<true, false, false, false, true><<<dim3(8, 32), 512, 0, stream>>>(
            h_bf, w1_t, b1_l, nullptr, hid_bf, nullptr, nullptr, ND, ND, NF, NF);

        // MLP2: 256x128 tile, K-split 4 -> grid (8, 8, 4)
        k_gemm_big<false, false, false, true, false><<<dim3(8, 8, 4), 512, 0, stream>>>(
            hid_bf, w2_t, nullptr, p03, nullptr, nullptr, nullptr, NF / 4, NF, ND, ND);
        k_combine4<<<NM, 256, 0, stream>>>(p03, b2_l, x);
    }

    k_layernorm<<<NM, 256, 0, stream>>>(x, lnf_g, lnf_b, h_bf);

    k_wtrans<<<dim3(NVPAD / 32, ND / 32), 256, 0, stream>>>(lm_w, lm_t, ND, NV, NVPAD, NV, NV);
    k_gemm_big<false, true, true, false, false><<<dim3(8, NVPAD / 128), 512, 0, stream>>>(
        h_bf, lm_t, lm_b, out, nullptr, pmax, psum, ND, ND, NV, NV);

    k_losscombine<<<NM / 4, 256, 0, stream>>>(pmax, psum, out, targets, rl);
    k_lossreduce<<<1, 256, 0, stream>>>(rl, out + (size_t)NM * NV);
}

// Round 15
// 1572.539 us; speedup vs baseline: 1.3254x; 1.0048x over previous
//
#include <hip/hip_runtime.h>
#include <cstdint>
#include <cstddef>

typedef unsigned short u16;
typedef unsigned int u32;
typedef __bf16 bf16x8 __attribute__((ext_vector_type(8)));
typedef float f32x4 __attribute__((ext_vector_type(4)));
typedef short short8_t __attribute__((ext_vector_type(8)));

#define NV 50257
#define NVPAD 50304   // 393 * 128
#define NBLK_LM 393
#define ND 1024
#define NT 1024
#define NH 16
#define NL 6
#define NB 2
#define NM 2048       // B*T
#define NF 4096       // 4*D
#define EPSLN 1e-5f

#define VMCNT(n) asm volatile("s_waitcnt vmcnt(" #n ")" ::: "memory")

__device__ __forceinline__ u16 f2bf(float f) {
    unsigned u = __float_as_uint(f);
    return (u16)((u + 0x7fffu + ((u >> 16) & 1u)) >> 16);   // RNE
}
__device__ __forceinline__ float bf2f(u16 h) {
    return __uint_as_float(((unsigned)h) << 16);
}
__device__ __forceinline__ u32 pack2bf(float lo, float hi) {
    return (u32)f2bf(lo) | ((u32)f2bf(hi) << 16);
}

__device__ __forceinline__ void gload_lds16(const u16* g, u16* l) {
    __builtin_amdgcn_global_load_lds((const __attribute__((address_space(1))) void*)g,
                                     (__attribute__((address_space(3))) void*)l, 16, 0, 0);
}

__device__ __forceinline__ float wave_reduce_sum(float v) {
#pragma unroll
    for (int off = 32; off >= 1; off >>= 1) v += __shfl_xor(v, off, 64);
    return v;
}

// ---------------- shared LN tail: given per-thread float4 v at col d, write LN ----------
__device__ __forceinline__ void ln_write(float4 v, int m, int d,
                                         const float* __restrict__ g,
                                         const float* __restrict__ b,
                                         u16* __restrict__ outb,
                                         float* ss, float* sq) {
    float s = v.x + v.y + v.z + v.w;
    float q = v.x * v.x + v.y * v.y + v.z * v.z + v.w * v.w;
    s = wave_reduce_sum(s);
    q = wave_reduce_sum(q);
    int lane = threadIdx.x & 63, w = threadIdx.x >> 6;
    if (lane == 0) { ss[w] = s; sq[w] = q; }
    __syncthreads();
    s = ss[0] + ss[1] + ss[2] + ss[3];
    q = sq[0] + sq[1] + sq[2] + sq[3];
    float mu = s * (1.0f / ND);
    float var = q * (1.0f / ND) - mu * mu;
    float rstd = rsqrtf(var + EPSLN);
    float4 gg = *(const float4*)(g + d);
    float4 bb = *(const float4*)(b + d);
    ushort4 pk;
    pk.x = f2bf((v.x - mu) * rstd * gg.x + bb.x);
    pk.y = f2bf((v.y - mu) * rstd * gg.y + bb.y);
    pk.z = f2bf((v.z - mu) * rstd * gg.z + bb.z);
    pk.w = f2bf((v.w - mu) * rstd * gg.w + bb.w);
    *(ushort4*)(outb + (size_t)m * ND + d) = pk;
}

// ---------------- embedding + LN1(layer0) fused ----------------
__global__ __launch_bounds__(256) void k_embed_ln(const int* __restrict__ idx,
                                                  const float* __restrict__ tok,
                                                  const float* __restrict__ pos,
                                                  const float* __restrict__ g,
                                                  const float* __restrict__ b,
                                                  float* __restrict__ x,
                                                  u16* __restrict__ outb) {
    __shared__ float ss[4], sq[4];
    int m = blockIdx.x;
    int t = m & (NT - 1);
    int tokid = idx[m];
    int d = threadIdx.x * 4;
    float4 a = *(const float4*)(tok + (size_t)tokid * ND + d);
    float4 p = *(const float4*)(pos + (size_t)t * ND + d);
    a.x += p.x; a.y += p.y; a.z += p.z; a.w += p.w;
    *(float4*)(x + (size_t)m * ND + d) = a;
    ln_write(a, m, d, g, b, outb, ss, sq);
}

// ---------------- layernorm (ln2 only now) ----------------
__global__ __launch_bounds__(256) void k_layernorm(const float* __restrict__ x,
                                                   const float* __restrict__ g,
                                                   const float* __restrict__ b,
                                                   u16* __restrict__ outb) {
    __shared__ float ss[4], sq[4];
    int m = blockIdx.x;
    int d = threadIdx.x * 4;
    const float4 v = *(const float4*)(x + (size_t)m * ND + d);
    ln_write(v, m, d, g, b, outb, ss, sq);
}

// ---------------- combine (x += p0..p3 + bias) fused with NEXT layer's LN ----------------
__global__ __launch_bounds__(256) void k_combine4_ln(const float* __restrict__ p,
                                                     const float* __restrict__ bias,
                                                     float* __restrict__ x,
                                                     const float* __restrict__ g,
                                                     const float* __restrict__ b,
                                                     u16* __restrict__ outb) {
    __shared__ float ss[4], sq[4];
    const int m = blockIdx.x;
    const int d = threadIdx.x * 4;
    const size_t off = (size_t)m * ND + d;
    float4 a  = *(const float4*)(x + off);
    float4 q0 = *(const float4*)(p + off);
    float4 q1 = *(const float4*)(p + (size_t)NM * ND + off);
    float4 q2 = *(const float4*)(p + (size_t)2 * NM * ND + off);
    float4 q3 = *(const float4*)(p + (size_t)3 * NM * ND + off);
    float4 bb = *(const float4*)(bias + d);
    a.x += ((q0.x + q1.x) + (q2.x + q3.x)) + bb.x;
    a.y += ((q0.y + q1.y) + (q2.y + q3.y)) + bb.y;
    a.z += ((q0.z + q1.z) + (q2.z + q3.z)) + bb.z;
    a.w += ((q0.w + q1.w) + (q2.w + q3.w)) + bb.w;
    *(float4*)(x + off) = a;
    ln_write(a, m, d, g, b, outb, ss, sq);
}

// ---------------- LM weight transpose + f32->bf16 (N-padded) ----------------
__global__ __launch_bounds__(256) void k_wtrans(const float* __restrict__ W,
                                                u16* __restrict__ Wt,
                                                int K, int N, int Npad, int hs, int ld) {
    __shared__ float t[32][33];
    const int nb = blockIdx.x << 5, kb = blockIdx.y << 5;
    const int tx = threadIdx.x & 31, tq = threadIdx.x >> 5;
    const int n = nb + tx;
    if (n < N) {
        const int head = n / hs, nc = n - head * hs;
        const float* src = W + (size_t)head * K * hs + nc;
#pragma unroll
        for (int i = 0; i < 4; ++i)
            t[(tq << 2) + i][tx] = src[(size_t)(kb + (tq << 2) + i) * ld];
    } else {
#pragma unroll
        for (int i = 0; i < 4; ++i) t[(tq << 2) + i][tx] = 0.f;
    }
    __syncthreads();
#pragma unroll
    for (int i = 0; i < 4; ++i) {
        const int nn = nb + (tq << 2) + i;
        if (nn < Npad) Wt[(size_t)nn * K + kb + tx] = f2bf(t[tx][(tq << 2) + i]);
    }
}

// ---------------- fused per-layer weight transpose (qkv + wp + w1 + w2) ----------------
__global__ __launch_bounds__(256) void k_wtrans_all(const float* __restrict__ Wq,
                                                    const float* __restrict__ Wk,
                                                    const float* __restrict__ Wv,
                                                    const float* __restrict__ Wp,
                                                    const float* __restrict__ W1,
                                                    const float* __restrict__ W2,
                                                    u16* __restrict__ Wqkvt,
                                                    u16* __restrict__ Wpt,
                                                    u16* __restrict__ W1t,
                                                    u16* __restrict__ W2t) {
    __shared__ float t[32][33];
    int bid = blockIdx.x;
    const int tx = threadIdx.x & 31, tq = threadIdx.x >> 5;
    if (bid < 3072) {
        const int z = bid >> 10;
        const float* W = (z == 0) ? Wq : (z == 1) ? Wk : Wv;
        u16* dst = Wqkvt + (size_t)z * ND * ND;
        bid &= 1023;
        const int nb = (bid & 31) << 5, kb = (bid >> 5) << 5;
        const int n = nb + tx;
        const int head = n >> 6, nc = n & 63;
        const float* src = W + (size_t)head * ND * 64 + nc;
#pragma unroll
        for (int i = 0; i < 4; ++i)
            t[(tq << 2) + i][tx] = src[(size_t)(kb + (tq << 2) + i) * 64];
        __syncthreads();
#pragma unroll
        for (int i = 0; i < 4; ++i)
            dst[(size_t)(nb + (tq << 2) + i) * ND + kb + tx] = f2bf(t[tx][(tq << 2) + i]);
        return;
    }
    const float* W; u16* Wt; int K, N, nb, kb;
    if (bid < 4096)      { W = Wp; Wt = Wpt; K = ND; N = ND; bid -= 3072;
                           nb = (bid & 31) << 5; kb = (bid >> 5) << 5; }
    else if (bid < 8192) { W = W1; Wt = W1t; K = ND; N = NF; bid -= 4096;
                           nb = (bid & 127) << 5; kb = (bid >> 7) << 5; }
    else                 { W = W2; Wt = W2t; K = NF; N = ND; bid -= 8192;
                           nb = (bid & 31) << 5; kb = (bid >> 5) << 5; }
#pragma unroll
    for (int i = 0; i < 4; ++i)
        t[(tq << 2) + i][tx] = W[(size_t)(kb + (tq << 2) + i) * N + nb + tx];
    __syncthreads();
#pragma unroll
    for (int i = 0; i < 4; ++i)
        Wt[(size_t)(nb + (tq << 2) + i) * K + kb + tx] = f2bf(t[tx][(tq << 2) + i]);
}

// ---------------- V transpose: qkv[B,T,3072] -> vt[B,H,64,T] (bf16) ----------------
__global__ __launch_bounds__(256) void k_vtrans(const u16* __restrict__ qkv,
                                                u16* __restrict__ vt) {
    __shared__ u16 L[64][72];
    const int tt = blockIdx.x, bh = blockIdx.y;
    const int b = bh >> 4, h = bh & 15;
    const int tid = threadIdx.x;
    const int tr = tid >> 2, dc = (tid & 3) << 4;
    const u16* src = qkv + (size_t)(b * NT + tt * 64 + tr) * 3072 + 2048 + h * 64 + dc;
    short8_t v0 = *(const short8_t*)src;
    short8_t v1 = *(const short8_t*)(src + 8);
#pragma unroll
    for (int j = 0; j < 8; ++j) { L[tr][dc + j] = (u16)v0[j]; L[tr][dc + 8 + j] = (u16)v1[j]; }
    __syncthreads();
    const int dr = tid >> 2, tc = (tid & 3) << 4;
    union { u16 us[16]; short8_t v[2]; } tmp;
#pragma unroll
    for (int j = 0; j < 16; ++j) tmp.us[j] = L[tc + j][dr];
    u16* dst = vt + ((size_t)bh * 64 + dr) * NT + tt * 64 + tc;
    *(short8_t*)dst = tmp.v[0];
    *(short8_t*)(dst + 8) = tmp.v[1];
}

// =====================================================================================
// 256x128-tile 2-phase MFMA GEMM, counted vmcnt barriers (R14 proven).
// =====================================================================================
template <bool RELU, bool NBOUND, bool PART, bool KSPLIT, bool OUTBF16>
__global__ __launch_bounds__(512) void k_gemm_big(
    const u16* __restrict__ A, const u16* __restrict__ Bt,
    const float* __restrict__ bias,
    float* __restrict__ Cf, u16* __restrict__ Cb,
    float* __restrict__ pmax_g, float* __restrict__ psum_g,
    int Ksub, int Ktot, int N, int ldc)
{
    __shared__ u16 As[2][256 * 32];
    __shared__ u16 Bs[2][128 * 32];
    const int lin = blockIdx.y * (int)gridDim.x + blockIdx.x;
    const int nwg = (int)gridDim.x * (int)gridDim.y;
    const int cpx = nwg >> 3;
    const int swz = (lin & 7) * cpx + (lin >> 3);
    const int m0 = (swz & 7) * 256;
    const int n0 = (swz >> 3) * 128;
    const int tid = threadIdx.x;
    const int lane = tid & 63, w = tid >> 6;
    const int wr = w >> 1, wc = w & 1;
    const int lr = lane & 15, kg = lane >> 4;

    const int srow = lane >> 2;
    const int scol = (((lane & 3) ^ ((lane >> 3) & 3)) << 3);
    const int koff = KSPLIT ? (int)blockIdx.z * Ksub : 0;
    const u16* gA0 = A + (size_t)(m0 + w * 16 + srow) * Ktot + koff + scol;
    const u16* gA1 = gA0 + (size_t)128 * Ktot;
    const u16* gB0 = Bt + (size_t)(n0 + w * 16 + srow) * Ktot + koff + scol;

    f32x4 acc[4][4] = {};
    const int nt = Ksub >> 5;

    gload_lds16(gA0, &As[0][w * 512]);
    gload_lds16(gA1, &As[0][4096 + w * 512]);
    gload_lds16(gB0, &Bs[0][w * 512]);

    int cur = 0;
    for (int t = 0; t < nt; ++t) {
        if (t + 1 < nt) {
            const int ko = (t + 1) << 5;
            gload_lds16(gA0 + ko, &As[cur ^ 1][w * 512]);
            gload_lds16(gA1 + ko, &As[cur ^ 1][4096 + w * 512]);
            gload_lds16(gB0 + ko, &Bs[cur ^ 1][w * 512]);
            VMCNT(3);
        } else {
            VMCNT(0);
        }
        __builtin_amdgcn_s_barrier();
        bf16x8 af[4], bfr[4];
        const int rsw = ((kg ^ ((lr >> 1) & 3)) << 3);
#pragma unroll
        for (int mi = 0; mi < 4; ++mi)
            af[mi] = *(const bf16x8*)&As[cur][(wr * 64 + mi * 16 + lr) * 32 + rsw];
#pragma unroll
        for (int ni = 0; ni < 4; ++ni)
            bfr[ni] = *(const bf16x8*)&Bs[cur][(wc * 64 + ni * 16 + lr) * 32 + rsw];
#pragma unroll
        for (int mi = 0; mi < 4; ++mi)
#pragma unroll
            for (int ni = 0; ni < 4; ++ni)
                acc[mi][ni] = __builtin_amdgcn_mfma_f32_16x16x32_bf16(af[mi], bfr[ni], acc[mi][ni], 0, 0, 0);
        __builtin_amdgcn_s_barrier();
        cur ^= 1;
    }

    float* Cz = KSPLIT ? (Cf + (size_t)blockIdx.z * NM * ldc) : Cf;
#pragma unroll
    for (int mi = 0; mi < 4; ++mi)
#pragma unroll
        for (int ni = 0; ni < 4; ++ni)
#pragma unroll
            for (int r = 0; r < 4; ++r) {
                const int row = m0 + wr * 64 + mi * 16 + kg * 4 + r;
                const int col = n0 + wc * 64 + ni * 16 + lr;
                if (NBOUND && col >= N) continue;
                float c = acc[mi][ni][r];
                if (bias) c += bias[col];
                if (RELU) c = fmaxf(c, 0.f);
                if (PART) acc[mi][ni][r] = c;
                if (OUTBF16) Cb[(size_t)row * ldc + col] = f2bf(c);
                else         Cz[(size_t)row * ldc + col] = c;
            }

    if constexpr (PART) {
        float* redm = (float*)As;            // [2][256]
        float* reds = redm + 512;            // [2][256]
#pragma unroll
        for (int mi = 0; mi < 4; ++mi)
#pragma unroll
            for (int r = 0; r < 4; ++r) {
                float vmax = -3.0e38f;
#pragma unroll
                for (int ni = 0; ni < 4; ++ni) {
                    const int col = n0 + wc * 64 + ni * 16 + lr;
                    vmax = fmaxf(vmax, (col < N) ? acc[mi][ni][r] : -3.0e38f);
                }
                vmax = fmaxf(vmax, __shfl_xor(vmax, 1));
                vmax = fmaxf(vmax, __shfl_xor(vmax, 2));
                vmax = fmaxf(vmax, __shfl_xor(vmax, 4));
                vmax = fmaxf(vmax, __shfl_xor(vmax, 8));
                if (lr == 0) redm[wc * 256 + wr * 64 + mi * 16 + kg * 4 + r] = vmax;
            }
        __syncthreads();
#pragma unroll
        for (int mi = 0; mi < 4; ++mi)
#pragma unroll
            for (int r = 0; r < 4; ++r) {
                const int rloc = wr * 64 + mi * 16 + kg * 4 + r;
                const float M = fmaxf(redm[rloc], redm[256 + rloc]);
                float s = 0.f;
#pragma unroll
                for (int ni = 0; ni < 4; ++ni) {
                    const int col = n0 + wc * 64 + ni * 16 + lr;
                    if (col < N) s += __expf(acc[mi][ni][r] - M);
                }
                s += __shfl_xor(s, 1);
                s += __shfl_xor(s, 2);
                s += __shfl_xor(s, 4);
                s += __shfl_xor(s, 8);
                if (lr == 0) reds[wc * 256 + rloc] = s;
            }
        __syncthreads();
        if (tid < 256) {
            const float M = fmaxf(redm[tid], redm[256 + tid]);
            const float S = reds[tid] + reds[256 + tid];
            const int nblk = n0 >> 7;
            pmax_g[(size_t)nblk * NM + m0 + tid] = M;
            psum_g[(size_t)nblk * NM + m0 + tid] = S;
        }
    }
}

// ---------------- 128x128 2-phase MFMA GEMM (QKV), counted vmcnt ----------------
template <bool RELU, bool NBOUND, bool OUTBF16>
__global__ __launch_bounds__(256) void k_mfma_gemm(
    const u16* __restrict__ A, const u16* __restrict__ Bt,
    const float* __restrict__ bias,
    float* __restrict__ Cf, u16* __restrict__ Cb,
    int K, int N, int ldc)
{
    __shared__ u16 As[2][128 * 32];
    __shared__ u16 Bs[2][128 * 32];
    const int lin = blockIdx.y * 16 + blockIdx.x;
    const int nwg = (int)gridDim.y * 16;
    const int cpx = nwg >> 3;
    const int swz = (lin & 7) * cpx + (lin >> 3);
    const int m0 = (swz & 15) * 128;
    const int n0 = (swz >> 4) * 128;
    const int tid = threadIdx.x;
    const int lane = tid & 63, wv = tid >> 6;
    const int wr = wv >> 1, wc = wv & 1;
    const int lr = lane & 15, kg = lane >> 4;

    const int srow = lane >> 2;
    const int scol = (((lane & 3) ^ ((lane >> 3) & 3)) << 3);
    const u16* gA0 = A + (size_t)(m0 + wv * 16 + srow) * K + scol;
    const u16* gA1 = gA0 + (size_t)64 * K;
    const u16* gB0 = Bt + (size_t)(n0 + wv * 16 + srow) * K + scol;
    const u16* gB1 = gB0 + (size_t)64 * K;

    f32x4 acc[4][4] = {};
    const int nt = K >> 5;

    gload_lds16(gA0, &As[0][wv * 512]);
    gload_lds16(gA1, &As[0][2048 + wv * 512]);
    gload_lds16(gB0, &Bs[0][wv * 512]);
    gload_lds16(gB1, &Bs[0][2048 + wv * 512]);

    int cur = 0;
    for (int t = 0; t < nt; ++t) {
        if (t + 1 < nt) {
            const int ko = (t + 1) << 5;
            gload_lds16(gA0 + ko, &As[cur ^ 1][wv * 512]);
            gload_lds16(gA1 + ko, &As[cur ^ 1][2048 + wv * 512]);
            gload_lds16(gB0 + ko, &Bs[cur ^ 1][wv * 512]);
            gload_lds16(gB1 + ko, &Bs[cur ^ 1][2048 + wv * 512]);
            VMCNT(4);
        } else {
            VMCNT(0);
        }
        __builtin_amdgcn_s_barrier();
        bf16x8 af[4], bfr[4];
        const int rsw = ((kg ^ ((lr >> 1) & 3)) << 3);
#pragma unroll
        for (int mi = 0; mi < 4; ++mi) {
            const int R = wr * 64 + mi * 16 + lr;
            af[mi] = *(const bf16x8*)&As[cur][R * 32 + rsw];
        }
#pragma unroll
        for (int ni = 0; ni < 4; ++ni) {
            const int R = wc * 64 + ni * 16 + lr;
            bfr[ni] = *(const bf16x8*)&Bs[cur][R * 32 + rsw];
        }
#pragma unroll
        for (int mi = 0; mi < 4; ++mi)
#pragma unroll
            for (int ni = 0; ni < 4; ++ni)
                acc[mi][ni] = __builtin_amdgcn_mfma_f32_16x16x32_bf16(af[mi], bfr[ni], acc[mi][ni], 0, 0, 0);
        __builtin_amdgcn_s_barrier();
        cur ^= 1;
    }
#pragma unroll
    for (int mi = 0; mi < 4; ++mi) {
#pragma unroll
        for (int ni = 0; ni < 4; ++ni) {
#pragma unroll
            for (int r = 0; r < 4; ++r) {
                const int row = m0 + wr * 64 + mi * 16 + kg * 4 + r;
                const int col = n0 + wc * 64 + ni * 16 + lr;
                if (NBOUND && col >= N) continue;
                float c = acc[mi][ni][r];
                if (bias) c += bias[col];
                if (RELU) c = fmaxf(c, 0.f);
                if (OUTBF16) Cb[(size_t)row * ldc + col] = f2bf(c);
                else         Cf[(size_t)row * ldc + col] = c;
            }
        }
    }
}

// ---------------- 128x64-tile MFMA GEMM (proj), counted vmcnt --------
template <bool RELU, bool RESID, bool OUTBF16>
__global__ __launch_bounds__(256) void k_gemm_n64(
    const u16* __restrict__ A, const u16* __restrict__ Bt,
    const float* __restrict__ bias, const float* __restrict__ resid,
    float* __restrict__ Cf, u16* __restrict__ Cb,
    int K, int ldc)
{
    __shared__ u16 As[2][128 * 32];
    __shared__ u16 Bs[2][64 * 32];
    const int lin = blockIdx.y * 16 + blockIdx.x;
    const int nwg = (int)gridDim.y * 16;
    const int cpx = nwg >> 3;
    const int swz = (lin & 7) * cpx + (lin >> 3);
    const int m0 = (swz & 15) * 128;
    const int n0 = (swz >> 4) * 64;
    const int tid = threadIdx.x;
    const int lane = tid & 63, wv = tid >> 6;
    const int lr = lane & 15, kg = lane >> 4;

    const int srow = lane >> 2;
    const int scol = (((lane & 3) ^ ((lane >> 3) & 3)) << 3);
    const u16* gA0 = A + (size_t)(m0 + wv * 32 + srow) * K + scol;
    const u16* gA1 = gA0 + (size_t)16 * K;
    const u16* gB0 = Bt + (size_t)(n0 + wv * 16 + srow) * K + scol;

    f32x4 acc[2][4] = {};
    const int nt = K >> 5;

    gload_lds16(gA0, &As[0][wv * 1024]);
    gload_lds16(gA1, &As[0][wv * 1024 + 512]);
    gload_lds16(gB0, &Bs[0][wv * 512]);

    int cur = 0;
    for (int t = 0; t < nt; ++t) {
        if (t + 1 < nt) {
            const int ko = (t + 1) << 5;
            gload_lds16(gA0 + ko, &As[cur ^ 1][wv * 1024]);
            gload_lds16(gA1 + ko, &As[cur ^ 1][wv * 1024 + 512]);
            gload_lds16(gB0 + ko, &Bs[cur ^ 1][wv * 512]);
            VMCNT(3);
        } else {
            VMCNT(0);
        }
        __builtin_amdgcn_s_barrier();
        bf16x8 af[2], bfr[4];
        const int rsw = ((kg ^ ((lr >> 1) & 3)) << 3);
#pragma unroll
        for (int mi = 0; mi < 2; ++mi)
            af[mi] = *(const bf16x8*)&As[cur][(wv * 32 + mi * 16 + lr) * 32 + rsw];
#pragma unroll
        for (int ni = 0; ni < 4; ++ni)
            bfr[ni] = *(const bf16x8*)&Bs[cur][(ni * 16 + lr) * 32 + rsw];
#pragma unroll
        for (int mi = 0; mi < 2; ++mi)
#pragma unroll
            for (int ni = 0; ni < 4; ++ni)
                acc[mi][ni] = __builtin_amdgcn_mfma_f32_16x16x32_bf16(af[mi], bfr[ni], acc[mi][ni], 0, 0, 0);
        __builtin_amdgcn_s_barrier();
        cur ^= 1;
    }
#pragma unroll
    for (int mi = 0; mi < 2; ++mi) {
#pragma unroll
        for (int ni = 0; ni < 4; ++ni) {
#pragma unroll
            for (int r = 0; r < 4; ++r) {
                const int row = m0 + wv * 32 + mi * 16 + kg * 4 + r;
                const int col = n0 + ni * 16 + lr;
                float c = acc[mi][ni][r];
                if (bias) c += bias[col];
                if (RELU) c = fmaxf(c, 0.f);
                if (RESID) c += resid[(size_t)row * ldc + col];
                if (OUTBF16) Cb[(size_t)row * ldc + col] = f2bf(c);
                else         Cf[(size_t)row * ldc + col] = c;
            }
        }
    }
}

// ---------------- MFMA flash attention: 3-buffer KV, counted vmcnt, skip-rescale ------
__global__ __launch_bounds__(256) void k_attn_mfma(const u16* __restrict__ qkv,
                                                   const u16* __restrict__ vt,
                                                   u16* __restrict__ ob) {
    const int qt = (blockIdx.y < 16) ? (int)blockIdx.x : 15 - (int)blockIdx.x;
    const int bh = blockIdx.y;
    const int b = bh >> 4, h = bh & 15;
    const int tid = threadIdx.x;
    const int lane = tid & 63, w = tid >> 6;
    const int lr = lane & 15, kg = lane >> 4;

    __shared__ u16 Qs[64 * 64];
    __shared__ u16 Ks[3][64 * 64];
    __shared__ u16 Vs[3][64 * 64];

    const int srow8 = lane >> 3;
    const int csw = ((lane & 7) ^ srow8) << 3;

    {
        const int r0 = w * 8 + srow8;
        gload_lds16(qkv + (size_t)(b * NT + qt * 64 + r0) * 3072 + h * 64 + csw, &Qs[w * 512]);
        gload_lds16(qkv + (size_t)(b * NT + qt * 64 + 32 + r0) * 3072 + h * 64 + csw, &Qs[2048 + w * 512]);
    }
#define STAGE_KV(bb, st)                                                                            \
    {                                                                                               \
        const int r0_ = w * 8 + srow8;                                                              \
        gload_lds16(qkv + (size_t)(b * NT + (st) * 64 + r0_) * 3072 + 1024 + h * 64 + csw,          \
                    &Ks[bb][w * 512]);                                                              \
        gload_lds16(qkv + (size_t)(b * NT + (st) * 64 + 32 + r0_) * 3072 + 1024 + h * 64 + csw,     \
                    &Ks[bb][2048 + w * 512]);                                                       \
        gload_lds16(vt + ((size_t)bh * 64 + r0_) * NT + (st) * 64 + csw, &Vs[bb][w * 512]);         \
        gload_lds16(vt + ((size_t)bh * 64 + 32 + r0_) * NT + (st) * 64 + csw,                       \
                    &Vs[bb][2048 + w * 512]);                                                       \
    }
    STAGE_KV(0, 0);
    if (qt >= 1) STAGE_KV(1, 1);
    if (qt == 0) { VMCNT(0); } else { VMCNT(4); }
    __builtin_amdgcn_s_barrier();

    bf16x8 qf[2];
    {
        const int qrow = w * 16 + lr;
#pragma unroll
        for (int ds_ = 0; ds_ < 2; ++ds_)
            qf[ds_] = *(const bf16x8*)&Qs[qrow * 64 + ((((ds_ << 2) + kg) ^ (lr & 7)) << 3)];
    }

    float mstate = -3.0e38f, lstate = 0.f;
    f32x4 acc_o[4] = {};
    const int qg = qt * 64 + w * 16 + lr;

    int cur = 0;
    for (int st = 0; st <= qt; ++st) {
        if (st > 0) {
            if (st < qt) { VMCNT(4); } else { VMCNT(0); }
            __builtin_amdgcn_s_barrier();
        }
        if (st + 2 <= qt) {
            int tgt = cur + 2; if (tgt >= 3) tgt -= 3;
            STAGE_KV(tgt, st + 2);
        }
        const bool diag = (st == qt);
        const int milim = diag ? w : 3;

        f32x4 acc_s[4] = {};
#pragma unroll
        for (int mi = 0; mi < 4; ++mi) {
            if (mi <= milim) {
                const int srw = mi * 16 + lr;
#pragma unroll
                for (int ds_ = 0; ds_ < 2; ++ds_) {
                    bf16x8 kf = *(const bf16x8*)&Ks[cur][srw * 64 + ((((ds_ << 2) + kg) ^ (lr & 7)) << 3)];
                    acc_s[mi] = __builtin_amdgcn_mfma_f32_16x16x32_bf16(kf, qf[ds_], acc_s[mi], 0, 0, 0);
                }
            }
        }
        float tilemax = -3.0e38f;
#pragma unroll
        for (int mi = 0; mi < 4; ++mi)
#pragma unroll
            for (int r = 0; r < 4; ++r) {
                float x_ = acc_s[mi][r] * 0.125f;
                const int sg = st * 64 + mi * 16 + kg * 4 + r;
                if (mi > milim || sg > qg) x_ = -3.0e38f;
                acc_s[mi][r] = x_;
                tilemax = fmaxf(tilemax, x_);
            }
        tilemax = fmaxf(tilemax, __shfl_xor(tilemax, 16));
        tilemax = fmaxf(tilemax, __shfl_xor(tilemax, 32));
        // exact skip: if no lane's max grew, mnew == mstate and rfac == 1 identically
        const bool noresc = __all(tilemax <= mstate);
        const float mnew = fmaxf(mstate, tilemax);
        float rfac = 1.f;
        if (!noresc) rfac = __expf(mstate - mnew);
        mstate = mnew;

        float psum = 0.f;
        u32 pk[4][2];
#pragma unroll
        for (int mi = 0; mi < 4; ++mi) {
            float p0 = __expf(acc_s[mi][0] - mnew);
            float p1 = __expf(acc_s[mi][1] - mnew);
            float p2 = __expf(acc_s[mi][2] - mnew);
            float p3 = __expf(acc_s[mi][3] - mnew);
            psum += p0 + p1 + p2 + p3;
            pk[mi][0] = pack2bf(p0, p1);
            pk[mi][1] = pack2bf(p2, p3);
        }
        psum += __shfl_xor(psum, 16);
        psum += __shfl_xor(psum, 32);
        lstate = lstate * rfac + psum;

        if (!noresc) {
            float rf[4];
#pragma unroll
            for (int r = 0; r < 4; ++r) rf[r] = __shfl(rfac, kg * 4 + r);
#pragma unroll
            for (int ni = 0; ni < 4; ++ni)
#pragma unroll
                for (int r = 0; r < 4; ++r) acc_o[ni][r] *= rf[r];
        }

        const int src0 = ((kg & 1) << 5) + lr;
        const int src1 = src0 + 16;
#pragma unroll
        for (int ks_ = 0; ks_ < 2; ++ks_) {
            const u32 lo_a = __shfl((int)pk[ks_ * 2][0], src0);
            const u32 lo_b = __shfl((int)pk[ks_ * 2][1], src0);
            const u32 lo_c = __shfl((int)pk[ks_ * 2][0], src1);
            const u32 lo_d = __shfl((int)pk[ks_ * 2][1], src1);
            const u32 hi_a = __shfl((int)pk[ks_ * 2 + 1][0], src0);
            const u32 hi_b = __shfl((int)pk[ks_ * 2 + 1][1], src0);
            const u32 hi_c = __shfl((int)pk[ks_ * 2 + 1][0], src1);
            const u32 hi_d = __shfl((int)pk[ks_ * 2 + 1][1], src1);
            union { u32 u[4]; bf16x8 v; } pa;
            pa.u[0] = (kg & 2) ? hi_a : lo_a;
            pa.u[1] = (kg & 2) ? hi_b : lo_b;
            pa.u[2] = (kg & 2) ? hi_c : lo_c;
            pa.u[3] = (kg & 2) ? hi_d : lo_d;
#pragma unroll
            for (int ni = 0; ni < 4; ++ni) {
                const int drow = ni * 16 + lr;
                bf16x8 vf = *(const bf16x8*)&Vs[cur][drow * 64 + ((((ks_ << 2) + kg) ^ (lr & 7)) << 3)];
                acc_o[ni] = __builtin_amdgcn_mfma_f32_16x16x32_bf16(pa.v, vf, acc_o[ni], 0, 0, 0);
            }
        }
        cur = (cur == 2) ? 0 : cur + 1;
    }

    float il[4];
#pragma unroll
    for (int r = 0; r < 4; ++r) il[r] = 1.0f / __shfl(lstate, kg * 4 + r);
#pragma unroll
    for (int ni = 0; ni < 4; ++ni)
#pragma unroll
        for (int r = 0; r < 4; ++r) {
            const int q2 = qt * 64 + w * 16 + kg * 4 + r;
            ob[(size_t)(b * NT + q2) * ND + h * 64 + ni * 16 + lr] = f2bf(acc_o[ni][r] * il[r]);
        }
#undef STAGE_KV
}

// ---------------- loss combine from per-block partials ([nblk][NM]) ----------------
__global__ __launch_bounds__(256) void k_losscombine(const float* __restrict__ pmax,
                                                     const float* __restrict__ psum,
                                                     const float* __restrict__ logits,
                                                     const int* __restrict__ targets,
                                                     float* __restrict__ rl) {
    const int row = blockIdx.x * 4 + (threadIdx.x >> 6);
    const int lane = threadIdx.x & 63;
    float M = -3.0e38f;
    for (int j = lane; j < NBLK_LM; j += 64) M = fmaxf(M, pmax[(size_t)j * NM + row]);
#pragma unroll
    for (int off = 32; off >= 1; off >>= 1) M = fmaxf(M, __shfl_xor(M, off, 64));
    float S = 0.f;
    for (int j = lane; j < NBLK_LM; j += 64)
        S += psum[(size_t)j * NM + row] * __expf(pmax[(size_t)j * NM + row] - M);
    S = wave_reduce_sum(S);
    if (lane == 0)
        rl[row] = M + logf(S) - logits[(size_t)row * NV + targets[row]];
}

__global__ __launch_bounds__(256) void k_lossreduce(const float* __restrict__ rl,
                                                    float* __restrict__ out_loss) {
    int tid = threadIdx.x;
    float s = 0.f;
    for (int j = tid; j < NM; j += 256) s += rl[j];
    s = wave_reduce_sum(s);
    __shared__ float sv[4];
    int lane = tid & 63, w = tid >> 6;
    if (lane == 0) sv[w] = s;
    __syncthreads();
    if (tid == 0) out_loss[0] = (sv[0] + sv[1] + sv[2] + sv[3]) * (1.0f / NM);
}

extern "C" void kernel_launch(void* const* d_in, const int* in_sizes, int n_in,
                              void* d_out, int out_size, void* d_ws, size_t ws_size,
                              hipStream_t stream) {
    const int* idx      = (const int*)d_in[0];
    const int* targets  = (const int*)d_in[1];
    const float* tok    = (const float*)d_in[2];
    const float* pos    = (const float*)d_in[3];
    const float* wq     = (const float*)d_in[4];
    const float* wk     = (const float*)d_in[5];
    const float* wv     = (const float*)d_in[6];
    const float* wproj  = (const float*)d_in[7];
    const float* bproj  = (const float*)d_in[8];
    const float* ln1_g  = (const float*)d_in[9];
    const float* ln1_b  = (const float*)d_in[10];
    const float* ln2_g  = (const float*)d_in[11];
    const float* ln2_b  = (const float*)d_in[12];
    const float* w1     = (const float*)d_in[13];
    const float* b1     = (const float*)d_in[14];
    const float* w2     = (const float*)d_in[15];
    const float* b2     = (const float*)d_in[16];
    const float* lnf_g  = (const float*)d_in[17];
    const float* lnf_b  = (const float*)d_in[18];
    const float* lm_w   = (const float*)d_in[19];
    const float* lm_b   = (const float*)d_in[20];
    float* out = (float*)d_out;

    char* wsb = (char*)d_ws;
    auto alloc = [&](size_t bytes) { char* p = wsb; wsb += (bytes + 255) & ~(size_t)255; return p; };
    float* x     = (float*)alloc((size_t)NM * ND * 4);
    u16* h_bf    = (u16*)  alloc((size_t)NM * ND * 2);
    float* rl    = (float*)alloc((size_t)NM * 4);
    float* pmax  = (float*)alloc((size_t)NBLK_LM * NM * 4);
    float* psum  = (float*)alloc((size_t)NBLK_LM * NM * 4);
    char* region = (char*)alloc((size_t)NVPAD * ND * 2);   // 103 MB, aliased
    u16* qkv_bf = (u16*)(region);
    u16* vt_bf  = (u16*)(region + ((size_t)12 << 20));
    u16* ob_bf  = (u16*)(region + ((size_t)16 << 20));
    u16* hid_bf = (u16*)(region + ((size_t)20 << 20));
    u16* wqkv_t = (u16*)(region + ((size_t)36 << 20));
    u16* wp_t   = (u16*)(region + ((size_t)42 << 20));
    u16* w1_t   = (u16*)(region + ((size_t)44 << 20));
    u16* w2_t   = (u16*)(region + ((size_t)52 << 20));
    float* p03  = (float*)(region + ((size_t)60 << 20));   // 4 x 8 MB f32 partials
    u16* lm_t   = (u16*)(region);                          // used only after the layer loop

    // embed + LN1(layer 0)
    k_embed_ln<<<NM, 256, 0, stream>>>(idx, tok, pos, ln1_g, ln1_b, x, h_bf);

    for (int l = 0; l < NL; ++l) {
        const float* wq_l = wq + (size_t)l * NH * ND * 64;
        const float* wk_l = wk + (size_t)l * NH * ND * 64;
        const float* wv_l = wv + (size_t)l * NH * ND * 64;
        const float* wp_l = wproj + (size_t)l * ND * ND;
        const float* bp_l = bproj + (size_t)l * ND;
        const float* w1_l = w1 + (size_t)l * ND * NF;
        const float* b1_l = b1 + (size_t)l * NF;
        const float* w2_l = w2 + (size_t)l * NF * ND;
        const float* b2_l = b2 + (size_t)l * ND;
        // next LN params (layer l+1's ln1, or lnf after the last layer)
        const float* gN = (l + 1 < NL) ? ln1_g + (size_t)(l + 1) * ND : lnf_g;
        const float* bN = (l + 1 < NL) ? ln1_b + (size_t)(l + 1) * ND : lnf_b;

        k_wtrans_all<<<12288, 256, 0, stream>>>(wq_l, wk_l, wv_l, wp_l, w1_l, w2_l,
                                                wqkv_t, wp_t, w1_t, w2_t);

        k_mfma_gemm<false, false, true><<<dim3(16, 24), 256, 0, stream>>>(
            h_bf, wqkv_t, nullptr, nullptr, qkv_bf, ND, 3 * ND, 3 * ND);

        k_vtrans<<<dim3(NT / 64, NB * NH), 256, 0, stream>>>(qkv_bf, vt_bf);
        k_attn_mfma<<<dim3(NT / 64, NB * NH), 256, 0, stream>>>(qkv_bf, vt_bf, ob_bf);

        k_gemm_n64<false, true, false><<<dim3(16, 16), 256, 0, stream>>>(
            ob_bf, wp_t, bp_l, x, x, nullptr, ND, ND);

        k_layernorm<<<NM, 256, 0, stream>>>(x, ln2_g + (size_t)l * ND, ln2_b + (size_t)l * ND, h_bf);

        // MLP1: 256x128 tile, grid 8x32 = 256 blocks
        k_gemm_big<true, false, false, false, true><<<dim3(8, 32), 512, 0, stream>>>(
            h_bf, w1_t, b1_l, nullptr, hid_bf, nullptr, nullptr, ND, ND, NF, NF);

        // MLP2: 256x128 tile, K-split 4 -> grid (8, 8, 4)
        k_gemm_big<false, false, false, true, false><<<dim3(8, 8, 4), 512, 0, stream>>>(
            hid_bf, w2_t, nullptr, p03, nullptr, nullptr, nullptr, NF / 4, NF, ND, ND);

        // x += partials + bias, fused with NEXT layer's LN (lnf after the last layer)
        k_combine4_ln<<<NM, 256, 0, stream>>>(p03, b2_l, x, gN, bN, h_bf);
    }

    k_wtrans<<<dim3(NVPAD / 32, ND / 32), 256, 0, stream>>>(lm_w, lm_t, ND, NV, NVPAD, NV, NV);
    k_gemm_big<false, true, true, false, false><<<dim3(8, NVPAD / 128), 512, 0, stream>>>(
        h_bf, lm_t, lm_b, out, nullptr, pmax, psum, ND, ND, NV, NV);

    k_losscombine<<<NM / 4, 256, 0, stream>>>(pmax, psum, out, targets, rl);
    k_lossreduce<<<1, 256, 0, stream>>>(rl, out + (size_t)NM * NV);
}